// Round 18
// baseline (320.671 us; speedup 1.0000x reference)
//
#include <hip/hip_runtime.h>

typedef unsigned short u16;
typedef __bf16 bf16_t;
typedef bf16_t bf16x8 __attribute__((ext_vector_type(8)));
typedef float f32x4 __attribute__((ext_vector_type(4)));

#define B_   8
#define CH   64
#define HW   2304
#define L2E  1.4426950408889634f

// ---- workspace byte offsets ----
#define OFF_XLC   0u          // bf16 [8][64][2304] channel-major
#define OFF_XRC   2359296u
#define OFF_XLT   4718592u    // bf16 [8][2304][64] position-major
#define OFF_XRT   7077888u
#define OFF_B1    9437184u    // f32  [8][64][2304]
#define OFF_B2    14155776u
#define OFF_RS2   18874368u   // f32  [8][2304]  1/S2[n]
// total 18948096 bytes

__device__ __forceinline__ float bf2f(u16 u){
  union { unsigned int i; float f; } v; v.i = ((unsigned int)u) << 16; return v.f;
}
__device__ __forceinline__ u16 f2bf(float f){
  union { float f; unsigned int i; } v; v.f = f;
  unsigned int r = v.i + 0x7FFFu + ((v.i >> 16) & 1u);
  return (u16)(r >> 16);
}
__device__ __forceinline__ void gload16(const void* g, void* l){
  __builtin_amdgcn_global_load_lds(
      (const __attribute__((address_space(1))) void*)g,
      (__attribute__((address_space(3))) void*)l, 16, 0, 0);
}

// ---------------- K1: xL/xR = W[64x128] @ concat(x_h,x_l) + b ----------------
// x-column hoisted into 128 VGPRs; weight rows contiguous -> s_load_dwordx16 prefetch.
// 1-D grid 576: b = bid%8 (XCD affinity); q=bid>>3: o0=(q&3)*16, side=(q>>2)&1, p=(q>>3)*256+t
__global__ __launch_bounds__(256, 3) void k_proj(
    const float* xlh, const float* xll, const float* xrh, const float* xrl,
    const float* wLl, const float* bLl, const float* wRr, const float* bRr,
    char* ws)
{
  int bid = blockIdx.x;
  int b   = bid & 7;
  int q   = bid >> 3;
  int o0  = (q & 3) * 16;
  int side= (q >> 2) & 1;
  int p   = (q >> 3) * 256 + threadIdx.x;
  const float* xh = (side ? xrh : xlh) + (size_t)b*CH*HW;
  const float* xl = (side ? xrl : xll) + (size_t)b*CH*HW;
  const float* w  = (side ? wRr : wLl);
  const float* bi = (side ? bRr : bLl);

  // hoist the thread's x column (128 values) into registers — all loads in flight
  float xv[128];
  #pragma unroll
  for (int c=0;c<64;c++) xv[c]    = xh[(size_t)c*HW + p];
  #pragma unroll
  for (int c=0;c<64;c++) xv[64+c] = xl[(size_t)c*HW + p];

  float acc[16];
  #pragma unroll
  for (int j=0;j<16;j++) acc[j] = bi[o0+j];
  // j outer: weight row contiguous (s_load_dwordx16 x8), c inner: pure FMA stream
  #pragma unroll
  for (int j=0;j<16;j++){
    const float* wr = &w[(size_t)(o0+j)*128];
    #pragma unroll
    for (int c=0;c<128;c++) acc[j] = fmaf(wr[c], xv[c], acc[j]);
  }

  u16* xc = (u16*)(ws + (side ? OFF_XRC : OFF_XLC)) + (size_t)b*CH*HW;
  u16* xt = (u16*)(ws + (side ? OFF_XRT : OFF_XLT)) + (size_t)b*HW*CH;
  unsigned int pk[8];
  #pragma unroll
  for (int j=0;j<8;j++){
    unsigned int lo16 = f2bf(acc[2*j]);
    unsigned int hi16 = f2bf(acc[2*j+1]);
    pk[j] = lo16 | (hi16 << 16);
    xc[(size_t)(o0+2*j  )*HW + p] = (u16)lo16;
    xc[(size_t)(o0+2*j+1)*HW + p] = (u16)hi16;
  }
  uint4* dst = (uint4*)&xt[(size_t)p*CH + o0];
  dst[0] = make_uint4(pk[0],pk[1],pk[2],pk[3]);
  dst[1] = make_uint4(pk[4],pk[5],pk[6],pk[7]);
}

// ---------------- K2: 1/S2[n]; 32 A-rows/block (regs), LDS-staged Y tiles ----------------
// 1-D grid 576: b = bid%8; r0 = (bid/8)*32; wave wv: m-cols [wv*576,+576) as 2 streams
__global__ __launch_bounds__(256, 4) void k_stats(char* ws)
{
  __shared__ alignas(16) char smraw[16384];   // 4KB per wave: P tile 2KB + Q tile 2KB
  __shared__ float part[4][2][4][4];
  int bid = blockIdx.x;
  int b   = bid & 7;
  int r0  = (bid >> 3) * 32;
  const char* Xb = ws + OFF_XLT + (size_t)b*HW*CH*2;   // rows n (A operand, regs)
  const char* Yb = ws + OFF_XRT + (size_t)b*HW*CH*2;   // reduce over m (staged)
  float* out = (float*)(ws + OFF_RS2) + b*HW;

  int lane = threadIdx.x & 63;
  int wv   = __builtin_amdgcn_readfirstlane(threadIdx.x >> 6);
  int lo = lane & 15, g = lane >> 4;
  int l = lane;

  const u16* Xu = (const u16*)Xb;
  bf16x8 aA0 = *(const bf16x8*)&Xu[(size_t)(r0+lo)*CH + 8*g];
  bf16x8 aA1 = *(const bf16x8*)&Xu[(size_t)(r0+lo)*CH + 32 + 8*g];
  bf16x8 aB0 = *(const bf16x8*)&Xu[(size_t)(r0+16+lo)*CH + 8*g];
  bf16x8 aB1 = *(const bf16x8*)&Xu[(size_t)(r0+16+lo)*CH + 32 + 8*g];

  // stage source offsets: inst j covers rows j*8..j*8+7; s(r)=r&7
  int ySrc[2];
  #pragma unroll
  for (int j=0;j<2;j++){
    int r = j*8 + (l>>3);
    ySrc[j] = r*128 + (((l&7) ^ (r&7)))*16;
  }
  char* myY = smraw + wv*4096;
  int jbP = wv*576, jbQ = jbP + 288;

  // read offsets: row lo, slot g / 4|g, s(lo)=lo&7
  int rdP0 = lo*128 + ((g      ^ (lo&7)))*16;
  int rdP1 = lo*128 + (((4|g)  ^ (lo&7)))*16;

  #define STAGE_S(i) do { \
    const char* gp = Yb + (size_t)(jbP + (i)*16)*128; \
    const char* gq = Yb + (size_t)(jbQ + (i)*16)*128; \
    gload16(gp + ySrc[0], myY + 0);    gload16(gp + ySrc[1], myY + 1024); \
    gload16(gq + ySrc[0], myY + 2048); gload16(gq + ySrc[1], myY + 3072); \
  } while(0)

  float sPA[4] = {0.f,0.f,0.f,0.f};
  float sQA[4] = {0.f,0.f,0.f,0.f};
  float sPB[4] = {0.f,0.f,0.f,0.f};
  float sQB[4] = {0.f,0.f,0.f,0.f};

  STAGE_S(0);
  for (int i = 0; i < 18; ++i){
    asm volatile("s_waitcnt vmcnt(0)" ::: "memory");
    __builtin_amdgcn_sched_barrier(0);
    bf16x8 bP0 = *(const bf16x8*)(myY + rdP0);
    bf16x8 bP1 = *(const bf16x8*)(myY + rdP1);
    bf16x8 bQ0 = *(const bf16x8*)(myY + 2048 + rdP0);
    bf16x8 bQ1 = *(const bf16x8*)(myY + 2048 + rdP1);
    asm volatile("s_waitcnt lgkmcnt(0)" ::: "memory");
    __builtin_amdgcn_sched_barrier(0);
    int inext = (i+1 < 18) ? i+1 : 0;
    STAGE_S(inext);
    __builtin_amdgcn_sched_barrier(0);
    f32x4 z4 = {0.f,0.f,0.f,0.f};
    f32x4 dPA = __builtin_amdgcn_mfma_f32_16x16x32_bf16(aA0, bP0, z4, 0,0,0);
    dPA = __builtin_amdgcn_mfma_f32_16x16x32_bf16(aA1, bP1, dPA, 0,0,0);
    f32x4 dQA = __builtin_amdgcn_mfma_f32_16x16x32_bf16(aA0, bQ0, z4, 0,0,0);
    dQA = __builtin_amdgcn_mfma_f32_16x16x32_bf16(aA1, bQ1, dQA, 0,0,0);
    f32x4 dPB = __builtin_amdgcn_mfma_f32_16x16x32_bf16(aB0, bP0, z4, 0,0,0);
    dPB = __builtin_amdgcn_mfma_f32_16x16x32_bf16(aB1, bP1, dPB, 0,0,0);
    f32x4 dQB = __builtin_amdgcn_mfma_f32_16x16x32_bf16(aB0, bQ0, z4, 0,0,0);
    dQB = __builtin_amdgcn_mfma_f32_16x16x32_bf16(aB1, bQ1, dQB, 0,0,0);
    #pragma unroll
    for (int r=0;r<4;r++){
      sPA[r] += exp2f(dPA[r]*L2E); sQA[r] += exp2f(dQA[r]*L2E);
      sPB[r] += exp2f(dPB[r]*L2E); sQB[r] += exp2f(dQB[r]*L2E);
    }
  }
  #undef STAGE_S
  float sA[4], sB[4];
  #pragma unroll
  for (int r=0;r<4;r++){ sA[r] = sPA[r] + sQA[r]; sB[r] = sPB[r] + sQB[r]; }
  #pragma unroll
  for (int mask = 1; mask < 16; mask <<= 1){
    #pragma unroll
    for (int r=0;r<4;r++){
      sA[r] += __shfl_xor(sA[r], mask, 64);
      sB[r] += __shfl_xor(sB[r], mask, 64);
    }
  }
  if (lo == 0){
    #pragma unroll
    for (int r=0;r<4;r++){ part[wv][0][g][r] = sA[r]; part[wv][1][g][r] = sB[r]; }
  }
  __syncthreads();
  if (threadIdx.x < 32){
    int t = threadIdx.x;
    int half = t >> 4, gg = (t & 15) >> 2, rr = t & 3;
    float sum = part[0][half][gg][rr] + part[1][half][gg][rr]
              + part[2][half][gg][rr] + part[3][half][gg][rr];
    out[r0 + 16*half + 4*gg + rr] = 1.0f / sum;
  }
}

// ---------------- K3: fused aff->P -> b1^T/b2^T; LDS-staged, per-wave private ----------------
// 1-D grid 576: b = bid%8; m0 = (bid/8)*32; wave wv: n-quarter, 18 steps of 32
__global__ __launch_bounds__(256, 3) void k_attn(char* ws)
{
  __shared__ alignas(16) char smraw[49152];   // 12KB/wave: A 4KB | BL 4KB | BR 4KB
  int bid  = blockIdx.x;
  int b    = bid & 7;
  int m0   = (bid >> 3) * 32;
  int lane = threadIdx.x & 63;
  int wv   = __builtin_amdgcn_readfirstlane(threadIdx.x >> 6);
  int lo = lane & 15, g = lane >> 4;
  int l = lane;

  const char* XLt = ws + OFF_XLT + (size_t)b*HW*CH*2;
  const char* XRt = ws + OFF_XRT + (size_t)b*HW*CH*2;
  const char* XLc = ws + OFF_XLC + (size_t)b*CH*HW*2;
  const char* XRc = ws + OFF_XRC + (size_t)b*CH*HW*2;
  const float* rs2 = (const float*)(ws + OFF_RS2) + b*HW;

  const u16* XRtu = (const u16*)XRt;
  bf16x8 fmA0 = *(const bf16x8*)&XRtu[(size_t)(m0+lo)*CH + 8*g];
  bf16x8 fmA1 = *(const bf16x8*)&XRtu[(size_t)(m0+lo)*CH + 32 + 8*g];
  bf16x8 fmB0 = *(const bf16x8*)&XRtu[(size_t)(m0+16+lo)*CH + 8*g];
  bf16x8 fmB1 = *(const bf16x8*)&XRtu[(size_t)(m0+16+lo)*CH + 32 + 8*g];

  // ---- stage source offsets (pre-swizzled global addresses) ----
  int aSrc[4], bSrc[4];
  #pragma unroll
  for (int j=0;j<4;j++){
    int r  = j*8 + (l>>3);
    int sa = (r&3) | (((r>>3)&1)<<2);
    aSrc[j] = r*128 + (((l&7) ^ sa))*16;            // + n0*128
    int c  = j*16 + (l>>2);
    int sb = (c>>1)&3;
    bSrc[j] = c*(HW*2) + (((l&3) ^ sb))*16;         // + n0*2
  }
  char* myA  = smraw + wv*12288;
  char* myBL = myA + 4096;
  char* myBR = myA + 8192;

  // ---- read offsets ----
  int pr  = ((lo>>2)<<3) + (lo&3);
  int sAr = (lo&3) | (((lo>>2)&1)<<2);
  int rdA00 = pr*128     + ((g     ^ sAr))*16;
  int rdA01 = pr*128     + (((4|g) ^ sAr))*16;
  int rdA10 = (pr+4)*128 + ((g     ^ sAr))*16;
  int rdA11 = (pr+4)*128 + (((4|g) ^ sAr))*16;
  int sBr = (lo>>1)&3;
  int rdB0 = (     lo)*64 + ((g ^ sBr))*16;
  int rdB1 = (16 + lo)*64 + ((g ^ sBr))*16;
  int rdB2 = (32 + lo)*64 + ((g ^ sBr))*16;
  int rdB3 = (48 + lo)*64 + ((g ^ sBr))*16;

  #define STAGE_A(n0v) do { \
    const char* gA = XLt + (size_t)(n0v)*128; \
    const char* gL = XLc + (size_t)(n0v)*2; \
    const char* gR = XRc + (size_t)(n0v)*2; \
    gload16(gA + aSrc[0], myA  + 0);    gload16(gA + aSrc[1], myA  + 1024); \
    gload16(gA + aSrc[2], myA  + 2048); gload16(gA + aSrc[3], myA  + 3072); \
    gload16(gL + bSrc[0], myBL + 0);    gload16(gL + bSrc[1], myBL + 1024); \
    gload16(gL + bSrc[2], myBL + 2048); gload16(gL + bSrc[3], myBL + 3072); \
    gload16(gR + bSrc[0], myBR + 0);    gload16(gR + bSrc[1], myBR + 1024); \
    gload16(gR + bSrc[2], myBR + 2048); gload16(gR + bSrc[3], myBR + 3072); \
  } while(0)

  f32x4 acc1A[4], acc2A[4], acc1B[4], acc2B[4];
  #pragma unroll
  for (int ct=0;ct<4;ct++){
    f32x4 z4 = {0.f,0.f,0.f,0.f};
    acc1A[ct]=z4; acc2A[ct]=z4; acc1B[ct]=z4; acc2B[ct]=z4;
  }
  float s1A = 0.f, s1B = 0.f;

  int nbeg = wv * 576;
  STAGE_A(nbeg);
  for (int s = 0; s < 18; ++s){
    int n0 = nbeg + s*32;
    asm volatile("s_waitcnt vmcnt(0)" ::: "memory");
    __builtin_amdgcn_sched_barrier(0);
    bf16x8 fa00 = *(const bf16x8*)(myA + rdA00);
    bf16x8 fa01 = *(const bf16x8*)(myA + rdA01);
    bf16x8 fa10 = *(const bf16x8*)(myA + rdA10);
    bf16x8 fa11 = *(const bf16x8*)(myA + rdA11);
    bf16x8 bL0 = *(const bf16x8*)(myBL + rdB0);
    bf16x8 bL1 = *(const bf16x8*)(myBL + rdB1);
    bf16x8 bL2 = *(const bf16x8*)(myBL + rdB2);
    bf16x8 bL3 = *(const bf16x8*)(myBL + rdB3);
    bf16x8 bR0 = *(const bf16x8*)(myBR + rdB0);
    bf16x8 bR1 = *(const bf16x8*)(myBR + rdB1);
    bf16x8 bR2 = *(const bf16x8*)(myBR + rdB2);
    bf16x8 bR3 = *(const bf16x8*)(myBR + rdB3);
    f32x4 r20 = *(const f32x4*)&rs2[n0 + 8*g];
    f32x4 r21 = *(const f32x4*)&rs2[n0 + 8*g + 4];
    asm volatile("s_waitcnt lgkmcnt(0)" ::: "memory");
    __builtin_amdgcn_sched_barrier(0);
    int n1 = (s+1 < 18) ? n0 + 32 : nbeg;
    STAGE_A(n1);
    __builtin_amdgcn_sched_barrier(0);

    f32x4 z4 = {0.f,0.f,0.f,0.f};
    f32x4 d0A = __builtin_amdgcn_mfma_f32_16x16x32_bf16(fa00, fmA0, z4, 0,0,0);
    d0A = __builtin_amdgcn_mfma_f32_16x16x32_bf16(fa01, fmA1, d0A, 0,0,0);
    f32x4 d1A = __builtin_amdgcn_mfma_f32_16x16x32_bf16(fa10, fmA0, z4, 0,0,0);
    d1A = __builtin_amdgcn_mfma_f32_16x16x32_bf16(fa11, fmA1, d1A, 0,0,0);
    f32x4 d0B = __builtin_amdgcn_mfma_f32_16x16x32_bf16(fa00, fmB0, z4, 0,0,0);
    d0B = __builtin_amdgcn_mfma_f32_16x16x32_bf16(fa01, fmB1, d0B, 0,0,0);
    f32x4 d1B = __builtin_amdgcn_mfma_f32_16x16x32_bf16(fa10, fmB0, z4, 0,0,0);
    d1B = __builtin_amdgcn_mfma_f32_16x16x32_bf16(fa11, fmB1, d1B, 0,0,0);

    bf16x8 pa1A, pa2A, pa1B, pa2B;
    #pragma unroll
    for (int r=0;r<4;r++){
      float e0 = exp2f(d0A[r]*L2E);
      float e1 = exp2f(d1A[r]*L2E);
      s1A += e0 + e1;
      pa1A[r]   = (bf16_t)e0;
      pa1A[r+4] = (bf16_t)e1;
      pa2A[r]   = (bf16_t)(e0 * r20[r]);
      pa2A[r+4] = (bf16_t)(e1 * r21[r]);
      float f0 = exp2f(d0B[r]*L2E);
      float f1 = exp2f(d1B[r]*L2E);
      s1B += f0 + f1;
      pa1B[r]   = (bf16_t)f0;
      pa1B[r+4] = (bf16_t)f1;
      pa2B[r]   = (bf16_t)(f0 * r20[r]);
      pa2B[r+4] = (bf16_t)(f1 * r21[r]);
    }
    acc1A[0] = __builtin_amdgcn_mfma_f32_16x16x32_bf16(pa1A, bL0, acc1A[0], 0,0,0);
    acc1A[1] = __builtin_amdgcn_mfma_f32_16x16x32_bf16(pa1A, bL1, acc1A[1], 0,0,0);
    acc1A[2] = __builtin_amdgcn_mfma_f32_16x16x32_bf16(pa1A, bL2, acc1A[2], 0,0,0);
    acc1A[3] = __builtin_amdgcn_mfma_f32_16x16x32_bf16(pa1A, bL3, acc1A[3], 0,0,0);
    acc2A[0] = __builtin_amdgcn_mfma_f32_16x16x32_bf16(pa2A, bR0, acc2A[0], 0,0,0);
    acc2A[1] = __builtin_amdgcn_mfma_f32_16x16x32_bf16(pa2A, bR1, acc2A[1], 0,0,0);
    acc2A[2] = __builtin_amdgcn_mfma_f32_16x16x32_bf16(pa2A, bR2, acc2A[2], 0,0,0);
    acc2A[3] = __builtin_amdgcn_mfma_f32_16x16x32_bf16(pa2A, bR3, acc2A[3], 0,0,0);
    acc1B[0] = __builtin_amdgcn_mfma_f32_16x16x32_bf16(pa1B, bL0, acc1B[0], 0,0,0);
    acc1B[1] = __builtin_amdgcn_mfma_f32_16x16x32_bf16(pa1B, bL1, acc1B[1], 0,0,0);
    acc1B[2] = __builtin_amdgcn_mfma_f32_16x16x32_bf16(pa1B, bL2, acc1B[2], 0,0,0);
    acc1B[3] = __builtin_amdgcn_mfma_f32_16x16x32_bf16(pa1B, bL3, acc1B[3], 0,0,0);
    acc2B[0] = __builtin_amdgcn_mfma_f32_16x16x32_bf16(pa2B, bR0, acc2B[0], 0,0,0);
    acc2B[1] = __builtin_amdgcn_mfma_f32_16x16x32_bf16(pa2B, bR1, acc2B[1], 0,0,0);
    acc2B[2] = __builtin_amdgcn_mfma_f32_16x16x32_bf16(pa2B, bR2, acc2B[2], 0,0,0);
    acc2B[3] = __builtin_amdgcn_mfma_f32_16x16x32_bf16(pa2B, bR3, acc2B[3], 0,0,0);
  }
  #undef STAGE_A

  // protect overlay: all waves must finish their staged loop before red[] reuse
  asm volatile("s_waitcnt vmcnt(0)" ::: "memory");
  __syncthreads();

  float (*red)[64][17] = (float (*)[64][17])smraw;                 // 17408 B
  float (*s1part)[32]  = (float (*)[32])(smraw + 17408);           // 512 B
  float* rs1inv        = (float*)(smraw + 17920);                  // 128 B

  // ---- S1 block reduction ----
  float s1Ar = s1A + __shfl_xor(s1A, 16, 64);
  s1Ar += __shfl_xor(s1Ar, 32, 64);
  float s1Br = s1B + __shfl_xor(s1B, 16, 64);
  s1Br += __shfl_xor(s1Br, 32, 64);
  if (lane < 16){ s1part[wv][lane] = s1Ar; s1part[wv][16+lane] = s1Br; }
  __syncthreads();
  if (threadIdx.x < 32){
    int t = threadIdx.x;
    float s = s1part[0][t] + s1part[1][t] + s1part[2][t] + s1part[3][t];
    rs1inv[t] = 1.0f / s;
  }
  __syncthreads();

  float* B1 = (float*)(ws + OFF_B1) + (size_t)b*CH*HW;
  float* B2 = (float*)(ws + OFF_B2) + (size_t)b*CH*HW;
  int rl = threadIdx.x & 63;
  int rv = threadIdx.x >> 6;

  #pragma unroll
  for (int v=0; v<16; ++v) red[wv][lane][v] = acc1A[v>>2][v&3];
  __syncthreads();
  #pragma unroll
  for (int k=0;k<4;k++){
    int v = rv + 4*k;
    float s = red[0][rl][v] + red[1][rl][v] + red[2][rl][v] + red[3][rl][v];
    int midx = ((rl>>4)<<2) + (v&3);
    int c = ((v>>2)<<4) + (rl & 15);
    B1[(size_t)c*HW + m0 + midx] = s * rs1inv[midx];
  }
  __syncthreads();
  #pragma unroll
  for (int v=0; v<16; ++v) red[wv][lane][v] = acc2A[v>>2][v&3];
  __syncthreads();
  #pragma unroll
  for (int k=0;k<4;k++){
    int v = rv + 4*k;
    float s = red[0][rl][v] + red[1][rl][v] + red[2][rl][v] + red[3][rl][v];
    int midx = ((rl>>4)<<2) + (v&3);
    int c = ((v>>2)<<4) + (rl & 15);
    B2[(size_t)c*HW + m0 + midx] = s;
  }
  __syncthreads();
  #pragma unroll
  for (int v=0; v<16; ++v) red[wv][lane][v] = acc1B[v>>2][v&3];
  __syncthreads();
  #pragma unroll
  for (int k=0;k<4;k++){
    int v = rv + 4*k;
    float s = red[0][rl][v] + red[1][rl][v] + red[2][rl][v] + red[3][rl][v];
    int midx = ((rl>>4)<<2) + (v&3);
    int c = ((v>>2)<<4) + (rl & 15);
    B1[(size_t)c*HW + m0 + 16 + midx] = s * rs1inv[16 + midx];
  }
  __syncthreads();
  #pragma unroll
  for (int v=0; v<16; ++v) red[wv][lane][v] = acc2B[v>>2][v&3];
  __syncthreads();
  #pragma unroll
  for (int k=0;k<4;k++){
    int v = rv + 4*k;
    float s = red[0][rl][v] + red[1][rl][v] + red[2][rl][v] + red[3][rl][v];
    int midx = ((rl>>4)<<2) + (v&3);
    int c = ((v>>2)<<4) + (rl & 15);
    B2[(size_t)c*HW + m0 + 16 + midx] = s;
  }
}

// ---------------- K4: gate + output convs; register-accumulated ----------------
// 1-D grid 576: b = bid%8 (XCD affinity)
__global__ __launch_bounds__(256) void k_out(
    char* ws,
    const float* gwL, const float* gbL, const float* gwR, const float* gbR,
    const float* wLo, const float* bLoi, const float* wRo, const float* bRoi,
    float* out)
{
  __shared__ float xT[64][64];
  __shared__ float bT[64][64];
  __shared__ float gpart[4][64];
  __shared__ float gLds[64];
  int bid = blockIdx.x;
  int b   = bid & 7;
  int q   = bid >> 3;
  int side= q & 1;
  int p0  = (q >> 1) * 64;
  int t = threadIdx.x;
  const float* braw = (const float*)(ws + (side ? OFF_B2 : OFF_B1)) + (size_t)b*CH*HW;
  const u16*   xc   = (const u16*)(ws + (side ? OFF_XRC : OFF_XLC)) + (size_t)b*CH*HW;
  const float* w    = side ? wRo : wLo;
  const float* gw   = side ? gwR : gwL;
  float        gb   = side ? gbR[0] : gbL[0];
  const float* bias = side ? bRoi : bLoi;

  #pragma unroll
  for (int i=0;i<16;i++){
    int flat = i*256 + t;
    int c = flat >> 6, pl = flat & 63;
    bT[c][pl] = braw[(size_t)c*HW + p0 + pl];
    xT[c][pl] = bf2f(xc[(size_t)c*HW + p0 + pl]);
  }
  __syncthreads();
  {
    int qq = t >> 6, pl = t & 63;
    float a = 0.f;
    #pragma unroll
    for (int c = 0; c < 16; c++) a = fmaf(gw[16*qq + c], bT[16*qq + c][pl], a);
    gpart[qq][pl] = a;
  }
  __syncthreads();
  if (t < 64){
    float x = gpart[0][t]+gpart[1][t]+gpart[2][t]+gpart[3][t] + gb;
    gLds[t] = 1.0f/(1.0f + exp2f(-x*L2E));    // sigmoid
  }
  __syncthreads();
  #pragma unroll
  for (int i=0;i<16;i++){
    int flat = i*256 + t;
    int c = flat >> 6, pl = flat & 63;
    bT[c][pl] *= gLds[pl];
  }
  __syncthreads();
  int wv = t >> 6;
  int lane = t & 63;
  float* outp = out + ((size_t)side*B_ + b)*CH*HW;

  float acc[16];
  #pragma unroll
  for (int oi=0;oi<16;oi++) acc[oi] = bias[wv*16 + oi];
  for (int c=0;c<64;c++){
    float xv = xT[c][lane];
    float bv = bT[c][lane];
    #pragma unroll
    for (int oi=0;oi<16;oi++){
      int o = wv*16 + oi;
      acc[oi] = fmaf(w[(size_t)o*128 + c],      xv, acc[oi]);
      acc[oi] = fmaf(w[(size_t)o*128 + 64 + c], bv, acc[oi]);
    }
  }
  #pragma unroll
  for (int oi=0;oi<16;oi++){
    int o = wv*16 + oi;
    outp[(size_t)o*HW + p0 + lane] = acc[oi];
  }
}

extern "C" void kernel_launch(void* const* d_in, const int* in_sizes, int n_in,
                              void* d_out, int out_size, void* d_ws, size_t ws_size,
                              hipStream_t stream)
{
  char* ws = (char*)d_ws;
  k_proj <<<576, 256, 0, stream>>>(
      (const float*)d_in[0], (const float*)d_in[1],
      (const float*)d_in[2], (const float*)d_in[3],
      (const float*)d_in[4], (const float*)d_in[5],
      (const float*)d_in[6], (const float*)d_in[7], ws);
  k_stats<<<576, 256, 0, stream>>>(ws);
  k_attn <<<576, 256, 0, stream>>>(ws);
  k_out  <<<576, 256, 0, stream>>>(
      ws,
      (const float*)d_in[8],  (const float*)d_in[9],
      (const float*)d_in[10], (const float*)d_in[11],
      (const float*)d_in[12], (const float*)d_in[13],
      (const float*)d_in[14], (const float*)d_in[15],
      (float*)d_out);
}

// Round 19
// 162.411 us; speedup vs baseline: 1.9744x; 1.9744x over previous
//
#include <hip/hip_runtime.h>

typedef unsigned short u16;
typedef __bf16 bf16_t;
typedef bf16_t bf16x8 __attribute__((ext_vector_type(8)));
typedef float f32x4 __attribute__((ext_vector_type(4)));

#define B_   8
#define CH   64
#define HW   2304
#define L2E  1.4426950408889634f

// ---- workspace byte offsets ----
#define OFF_XLC   0u          // bf16 [8][64][2304] channel-major
#define OFF_XRC   2359296u
#define OFF_XLT   4718592u    // bf16 [8][2304][64] position-major
#define OFF_XRT   7077888u
#define OFF_B1    9437184u    // f32  [8][64][2304]
#define OFF_B2    14155776u
#define OFF_RS2   18874368u   // f32  [8][2304]  1/S2[n]
// total 18948096 bytes

__device__ __forceinline__ float bf2f(u16 u){
  union { unsigned int i; float f; } v; v.i = ((unsigned int)u) << 16; return v.f;
}
__device__ __forceinline__ u16 f2bf(float f){
  union { float f; unsigned int i; } v; v.f = f;
  unsigned int r = v.i + 0x7FFFu + ((v.i >> 16) & 1u);
  return (u16)(r >> 16);
}
__device__ __forceinline__ void gload16(const void* g, void* l){
  __builtin_amdgcn_global_load_lds(
      (const __attribute__((address_space(1))) void*)g,
      (__attribute__((address_space(3))) void*)l, 16, 0, 0);
}

// ---------------- K1: xL/xR = W[64x128] @ concat(x_h,x_l) + b ----------------
// r16 form: c-outer streaming x (coalesced VMEM), scalar weight loads, 16 outs/thread.
// 1-D grid 576: b = bid%8 (XCD affinity); q=bid>>3: o0=(q&3)*16, side=(q>>2)&1, p=(q>>3)*256+t
__global__ __launch_bounds__(256) void k_proj(
    const float* xlh, const float* xll, const float* xrh, const float* xrl,
    const float* wLl, const float* bLl, const float* wRr, const float* bRr,
    char* ws)
{
  int bid = blockIdx.x;
  int b   = bid & 7;
  int q   = bid >> 3;
  int o0  = (q & 3) * 16;
  int side= (q >> 2) & 1;
  int p   = (q >> 3) * 256 + threadIdx.x;
  const float* xh = (side ? xrh : xlh) + (size_t)b*CH*HW;
  const float* xl = (side ? xrl : xll) + (size_t)b*CH*HW;
  const float* w  = (side ? wRr : wLl);
  const float* bi = (side ? bRr : bLl);

  float acc[16];
  #pragma unroll
  for (int j=0;j<16;j++) acc[j] = bi[o0+j];
  for (int c=0;c<64;c++){
    float xv = xh[(size_t)c*HW + p];
    #pragma unroll
    for (int j=0;j<16;j++) acc[j] = fmaf(w[(size_t)(o0+j)*128 + c], xv, acc[j]);
  }
  for (int c=0;c<64;c++){
    float xv = xl[(size_t)c*HW + p];
    #pragma unroll
    for (int j=0;j<16;j++) acc[j] = fmaf(w[(size_t)(o0+j)*128 + 64 + c], xv, acc[j]);
  }
  u16* xc = (u16*)(ws + (side ? OFF_XRC : OFF_XLC)) + (size_t)b*CH*HW;
  u16* xt = (u16*)(ws + (side ? OFF_XRT : OFF_XLT)) + (size_t)b*HW*CH;
  unsigned int pk[8];
  #pragma unroll
  for (int j=0;j<8;j++){
    unsigned int lo16 = f2bf(acc[2*j]);
    unsigned int hi16 = f2bf(acc[2*j+1]);
    pk[j] = lo16 | (hi16 << 16);
    xc[(size_t)(o0+2*j  )*HW + p] = (u16)lo16;
    xc[(size_t)(o0+2*j+1)*HW + p] = (u16)hi16;
  }
  uint4* dst = (uint4*)&xt[(size_t)p*CH + o0];
  dst[0] = make_uint4(pk[0],pk[1],pk[2],pk[3]);
  dst[1] = make_uint4(pk[4],pk[5],pk[6],pk[7]);
}

// ---------------- K2: 1/S2[n]; 32 A-rows/block (regs), LDS-staged Y tiles ----------------
// 1-D grid 576: b = bid%8; r0 = (bid/8)*32; wave wv: m-cols [wv*576,+576) as 2 streams
__global__ __launch_bounds__(256, 4) void k_stats(char* ws)
{
  __shared__ alignas(16) char smraw[16384];   // 4KB per wave: P tile 2KB + Q tile 2KB
  __shared__ float part[4][2][4][4];
  int bid = blockIdx.x;
  int b   = bid & 7;
  int r0  = (bid >> 3) * 32;
  const char* Xb = ws + OFF_XLT + (size_t)b*HW*CH*2;   // rows n (A operand, regs)
  const char* Yb = ws + OFF_XRT + (size_t)b*HW*CH*2;   // reduce over m (staged)
  float* out = (float*)(ws + OFF_RS2) + b*HW;

  int lane = threadIdx.x & 63;
  int wv   = __builtin_amdgcn_readfirstlane(threadIdx.x >> 6);
  int lo = lane & 15, g = lane >> 4;
  int l = lane;

  const u16* Xu = (const u16*)Xb;
  bf16x8 aA0 = *(const bf16x8*)&Xu[(size_t)(r0+lo)*CH + 8*g];
  bf16x8 aA1 = *(const bf16x8*)&Xu[(size_t)(r0+lo)*CH + 32 + 8*g];
  bf16x8 aB0 = *(const bf16x8*)&Xu[(size_t)(r0+16+lo)*CH + 8*g];
  bf16x8 aB1 = *(const bf16x8*)&Xu[(size_t)(r0+16+lo)*CH + 32 + 8*g];

  // stage source offsets: inst j covers rows j*8..j*8+7; s(r)=r&7
  int ySrc[2];
  #pragma unroll
  for (int j=0;j<2;j++){
    int r = j*8 + (l>>3);
    ySrc[j] = r*128 + (((l&7) ^ (r&7)))*16;
  }
  char* myY = smraw + wv*4096;
  int jbP = wv*576, jbQ = jbP + 288;

  // read offsets: row lo, slot g / 4|g, s(lo)=lo&7
  int rdP0 = lo*128 + ((g      ^ (lo&7)))*16;
  int rdP1 = lo*128 + (((4|g)  ^ (lo&7)))*16;

  #define STAGE_S(i) do { \
    const char* gp = Yb + (size_t)(jbP + (i)*16)*128; \
    const char* gq = Yb + (size_t)(jbQ + (i)*16)*128; \
    gload16(gp + ySrc[0], myY + 0);    gload16(gp + ySrc[1], myY + 1024); \
    gload16(gq + ySrc[0], myY + 2048); gload16(gq + ySrc[1], myY + 3072); \
  } while(0)

  float sPA[4] = {0.f,0.f,0.f,0.f};
  float sQA[4] = {0.f,0.f,0.f,0.f};
  float sPB[4] = {0.f,0.f,0.f,0.f};
  float sQB[4] = {0.f,0.f,0.f,0.f};

  STAGE_S(0);
  for (int i = 0; i < 18; ++i){
    asm volatile("s_waitcnt vmcnt(0)" ::: "memory");
    __builtin_amdgcn_sched_barrier(0);
    bf16x8 bP0 = *(const bf16x8*)(myY + rdP0);
    bf16x8 bP1 = *(const bf16x8*)(myY + rdP1);
    bf16x8 bQ0 = *(const bf16x8*)(myY + 2048 + rdP0);
    bf16x8 bQ1 = *(const bf16x8*)(myY + 2048 + rdP1);
    asm volatile("s_waitcnt lgkmcnt(0)" ::: "memory");
    __builtin_amdgcn_sched_barrier(0);
    int inext = (i+1 < 18) ? i+1 : 0;
    STAGE_S(inext);
    __builtin_amdgcn_sched_barrier(0);
    f32x4 z4 = {0.f,0.f,0.f,0.f};
    f32x4 dPA = __builtin_amdgcn_mfma_f32_16x16x32_bf16(aA0, bP0, z4, 0,0,0);
    dPA = __builtin_amdgcn_mfma_f32_16x16x32_bf16(aA1, bP1, dPA, 0,0,0);
    f32x4 dQA = __builtin_amdgcn_mfma_f32_16x16x32_bf16(aA0, bQ0, z4, 0,0,0);
    dQA = __builtin_amdgcn_mfma_f32_16x16x32_bf16(aA1, bQ1, dQA, 0,0,0);
    f32x4 dPB = __builtin_amdgcn_mfma_f32_16x16x32_bf16(aB0, bP0, z4, 0,0,0);
    dPB = __builtin_amdgcn_mfma_f32_16x16x32_bf16(aB1, bP1, dPB, 0,0,0);
    f32x4 dQB = __builtin_amdgcn_mfma_f32_16x16x32_bf16(aB0, bQ0, z4, 0,0,0);
    dQB = __builtin_amdgcn_mfma_f32_16x16x32_bf16(aB1, bQ1, dQB, 0,0,0);
    #pragma unroll
    for (int r=0;r<4;r++){
      sPA[r] += exp2f(dPA[r]*L2E); sQA[r] += exp2f(dQA[r]*L2E);
      sPB[r] += exp2f(dPB[r]*L2E); sQB[r] += exp2f(dQB[r]*L2E);
    }
  }
  #undef STAGE_S
  float sA[4], sB[4];
  #pragma unroll
  for (int r=0;r<4;r++){ sA[r] = sPA[r] + sQA[r]; sB[r] = sPB[r] + sQB[r]; }
  #pragma unroll
  for (int mask = 1; mask < 16; mask <<= 1){
    #pragma unroll
    for (int r=0;r<4;r++){
      sA[r] += __shfl_xor(sA[r], mask, 64);
      sB[r] += __shfl_xor(sB[r], mask, 64);
    }
  }
  if (lo == 0){
    #pragma unroll
    for (int r=0;r<4;r++){ part[wv][0][g][r] = sA[r]; part[wv][1][g][r] = sB[r]; }
  }
  __syncthreads();
  if (threadIdx.x < 32){
    int t = threadIdx.x;
    int half = t >> 4, gg = (t & 15) >> 2, rr = t & 3;
    float sum = part[0][half][gg][rr] + part[1][half][gg][rr]
              + part[2][half][gg][rr] + part[3][half][gg][rr];
    out[r0 + 16*half + 4*gg + rr] = 1.0f / sum;
  }
}

// ---------------- K3: fused aff->P -> b1^T/b2^T; LDS-staged, per-wave private ----------------
// 1-D grid 576: b = bid%8; m0 = (bid/8)*32; wave wv: n-quarter, 18 steps of 32
__global__ __launch_bounds__(256, 3) void k_attn(char* ws)
{
  __shared__ alignas(16) char smraw[49152];   // 12KB/wave: A 4KB | BL 4KB | BR 4KB
  int bid  = blockIdx.x;
  int b    = bid & 7;
  int m0   = (bid >> 3) * 32;
  int lane = threadIdx.x & 63;
  int wv   = __builtin_amdgcn_readfirstlane(threadIdx.x >> 6);
  int lo = lane & 15, g = lane >> 4;
  int l = lane;

  const char* XLt = ws + OFF_XLT + (size_t)b*HW*CH*2;
  const char* XRt = ws + OFF_XRT + (size_t)b*HW*CH*2;
  const char* XLc = ws + OFF_XLC + (size_t)b*CH*HW*2;
  const char* XRc = ws + OFF_XRC + (size_t)b*CH*HW*2;
  const float* rs2 = (const float*)(ws + OFF_RS2) + b*HW;

  const u16* XRtu = (const u16*)XRt;
  bf16x8 fmA0 = *(const bf16x8*)&XRtu[(size_t)(m0+lo)*CH + 8*g];
  bf16x8 fmA1 = *(const bf16x8*)&XRtu[(size_t)(m0+lo)*CH + 32 + 8*g];
  bf16x8 fmB0 = *(const bf16x8*)&XRtu[(size_t)(m0+16+lo)*CH + 8*g];
  bf16x8 fmB1 = *(const bf16x8*)&XRtu[(size_t)(m0+16+lo)*CH + 32 + 8*g];

  // ---- stage source offsets (pre-swizzled global addresses) ----
  int aSrc[4], bSrc[4];
  #pragma unroll
  for (int j=0;j<4;j++){
    int r  = j*8 + (l>>3);
    int sa = (r&3) | (((r>>3)&1)<<2);
    aSrc[j] = r*128 + (((l&7) ^ sa))*16;            // + n0*128
    int c  = j*16 + (l>>2);
    int sb = (c>>1)&3;
    bSrc[j] = c*(HW*2) + (((l&3) ^ sb))*16;         // + n0*2
  }
  char* myA  = smraw + wv*12288;
  char* myBL = myA + 4096;
  char* myBR = myA + 8192;

  // ---- read offsets ----
  int pr  = ((lo>>2)<<3) + (lo&3);
  int sAr = (lo&3) | (((lo>>2)&1)<<2);
  int rdA00 = pr*128     + ((g     ^ sAr))*16;
  int rdA01 = pr*128     + (((4|g) ^ sAr))*16;
  int rdA10 = (pr+4)*128 + ((g     ^ sAr))*16;
  int rdA11 = (pr+4)*128 + (((4|g) ^ sAr))*16;
  int sBr = (lo>>1)&3;
  int rdB0 = (     lo)*64 + ((g ^ sBr))*16;
  int rdB1 = (16 + lo)*64 + ((g ^ sBr))*16;
  int rdB2 = (32 + lo)*64 + ((g ^ sBr))*16;
  int rdB3 = (48 + lo)*64 + ((g ^ sBr))*16;

  #define STAGE_A(n0v) do { \
    const char* gA = XLt + (size_t)(n0v)*128; \
    const char* gL = XLc + (size_t)(n0v)*2; \
    const char* gR = XRc + (size_t)(n0v)*2; \
    gload16(gA + aSrc[0], myA  + 0);    gload16(gA + aSrc[1], myA  + 1024); \
    gload16(gA + aSrc[2], myA  + 2048); gload16(gA + aSrc[3], myA  + 3072); \
    gload16(gL + bSrc[0], myBL + 0);    gload16(gL + bSrc[1], myBL + 1024); \
    gload16(gL + bSrc[2], myBL + 2048); gload16(gL + bSrc[3], myBL + 3072); \
    gload16(gR + bSrc[0], myBR + 0);    gload16(gR + bSrc[1], myBR + 1024); \
    gload16(gR + bSrc[2], myBR + 2048); gload16(gR + bSrc[3], myBR + 3072); \
  } while(0)

  f32x4 acc1A[4], acc2A[4], acc1B[4], acc2B[4];
  #pragma unroll
  for (int ct=0;ct<4;ct++){
    f32x4 z4 = {0.f,0.f,0.f,0.f};
    acc1A[ct]=z4; acc2A[ct]=z4; acc1B[ct]=z4; acc2B[ct]=z4;
  }
  float s1A = 0.f, s1B = 0.f;

  int nbeg = wv * 576;
  STAGE_A(nbeg);
  for (int s = 0; s < 18; ++s){
    int n0 = nbeg + s*32;
    asm volatile("s_waitcnt vmcnt(0)" ::: "memory");
    __builtin_amdgcn_sched_barrier(0);
    bf16x8 fa00 = *(const bf16x8*)(myA + rdA00);
    bf16x8 fa01 = *(const bf16x8*)(myA + rdA01);
    bf16x8 fa10 = *(const bf16x8*)(myA + rdA10);
    bf16x8 fa11 = *(const bf16x8*)(myA + rdA11);
    bf16x8 bL0 = *(const bf16x8*)(myBL + rdB0);
    bf16x8 bL1 = *(const bf16x8*)(myBL + rdB1);
    bf16x8 bL2 = *(const bf16x8*)(myBL + rdB2);
    bf16x8 bL3 = *(const bf16x8*)(myBL + rdB3);
    bf16x8 bR0 = *(const bf16x8*)(myBR + rdB0);
    bf16x8 bR1 = *(const bf16x8*)(myBR + rdB1);
    bf16x8 bR2 = *(const bf16x8*)(myBR + rdB2);
    bf16x8 bR3 = *(const bf16x8*)(myBR + rdB3);
    f32x4 r20 = *(const f32x4*)&rs2[n0 + 8*g];
    f32x4 r21 = *(const f32x4*)&rs2[n0 + 8*g + 4];
    asm volatile("s_waitcnt lgkmcnt(0)" ::: "memory");
    __builtin_amdgcn_sched_barrier(0);
    int n1 = (s+1 < 18) ? n0 + 32 : nbeg;
    STAGE_A(n1);
    __builtin_amdgcn_sched_barrier(0);

    f32x4 z4 = {0.f,0.f,0.f,0.f};
    f32x4 d0A = __builtin_amdgcn_mfma_f32_16x16x32_bf16(fa00, fmA0, z4, 0,0,0);
    d0A = __builtin_amdgcn_mfma_f32_16x16x32_bf16(fa01, fmA1, d0A, 0,0,0);
    f32x4 d1A = __builtin_amdgcn_mfma_f32_16x16x32_bf16(fa10, fmA0, z4, 0,0,0);
    d1A = __builtin_amdgcn_mfma_f32_16x16x32_bf16(fa11, fmA1, d1A, 0,0,0);
    f32x4 d0B = __builtin_amdgcn_mfma_f32_16x16x32_bf16(fa00, fmB0, z4, 0,0,0);
    d0B = __builtin_amdgcn_mfma_f32_16x16x32_bf16(fa01, fmB1, d0B, 0,0,0);
    f32x4 d1B = __builtin_amdgcn_mfma_f32_16x16x32_bf16(fa10, fmB0, z4, 0,0,0);
    d1B = __builtin_amdgcn_mfma_f32_16x16x32_bf16(fa11, fmB1, d1B, 0,0,0);

    bf16x8 pa1A, pa2A, pa1B, pa2B;
    #pragma unroll
    for (int r=0;r<4;r++){
      float e0 = exp2f(d0A[r]*L2E);
      float e1 = exp2f(d1A[r]*L2E);
      s1A += e0 + e1;
      pa1A[r]   = (bf16_t)e0;
      pa1A[r+4] = (bf16_t)e1;
      pa2A[r]   = (bf16_t)(e0 * r20[r]);
      pa2A[r+4] = (bf16_t)(e1 * r21[r]);
      float f0 = exp2f(d0B[r]*L2E);
      float f1 = exp2f(d1B[r]*L2E);
      s1B += f0 + f1;
      pa1B[r]   = (bf16_t)f0;
      pa1B[r+4] = (bf16_t)f1;
      pa2B[r]   = (bf16_t)(f0 * r20[r]);
      pa2B[r+4] = (bf16_t)(f1 * r21[r]);
    }
    acc1A[0] = __builtin_amdgcn_mfma_f32_16x16x32_bf16(pa1A, bL0, acc1A[0], 0,0,0);
    acc1A[1] = __builtin_amdgcn_mfma_f32_16x16x32_bf16(pa1A, bL1, acc1A[1], 0,0,0);
    acc1A[2] = __builtin_amdgcn_mfma_f32_16x16x32_bf16(pa1A, bL2, acc1A[2], 0,0,0);
    acc1A[3] = __builtin_amdgcn_mfma_f32_16x16x32_bf16(pa1A, bL3, acc1A[3], 0,0,0);
    acc2A[0] = __builtin_amdgcn_mfma_f32_16x16x32_bf16(pa2A, bR0, acc2A[0], 0,0,0);
    acc2A[1] = __builtin_amdgcn_mfma_f32_16x16x32_bf16(pa2A, bR1, acc2A[1], 0,0,0);
    acc2A[2] = __builtin_amdgcn_mfma_f32_16x16x32_bf16(pa2A, bR2, acc2A[2], 0,0,0);
    acc2A[3] = __builtin_amdgcn_mfma_f32_16x16x32_bf16(pa2A, bR3, acc2A[3], 0,0,0);
    acc1B[0] = __builtin_amdgcn_mfma_f32_16x16x32_bf16(pa1B, bL0, acc1B[0], 0,0,0);
    acc1B[1] = __builtin_amdgcn_mfma_f32_16x16x32_bf16(pa1B, bL1, acc1B[1], 0,0,0);
    acc1B[2] = __builtin_amdgcn_mfma_f32_16x16x32_bf16(pa1B, bL2, acc1B[2], 0,0,0);
    acc1B[3] = __builtin_amdgcn_mfma_f32_16x16x32_bf16(pa1B, bL3, acc1B[3], 0,0,0);
    acc2B[0] = __builtin_amdgcn_mfma_f32_16x16x32_bf16(pa2B, bR0, acc2B[0], 0,0,0);
    acc2B[1] = __builtin_amdgcn_mfma_f32_16x16x32_bf16(pa2B, bR1, acc2B[1], 0,0,0);
    acc2B[2] = __builtin_amdgcn_mfma_f32_16x16x32_bf16(pa2B, bR2, acc2B[2], 0,0,0);
    acc2B[3] = __builtin_amdgcn_mfma_f32_16x16x32_bf16(pa2B, bR3, acc2B[3], 0,0,0);
  }
  #undef STAGE_A

  // protect overlay: all waves must finish their staged loop before red[] reuse
  asm volatile("s_waitcnt vmcnt(0)" ::: "memory");
  __syncthreads();

  float (*red)[64][17] = (float (*)[64][17])smraw;                 // 17408 B
  float (*s1part)[32]  = (float (*)[32])(smraw + 17408);           // 512 B
  float* rs1inv        = (float*)(smraw + 17920);                  // 128 B

  // ---- S1 block reduction ----
  float s1Ar = s1A + __shfl_xor(s1A, 16, 64);
  s1Ar += __shfl_xor(s1Ar, 32, 64);
  float s1Br = s1B + __shfl_xor(s1B, 16, 64);
  s1Br += __shfl_xor(s1Br, 32, 64);
  if (lane < 16){ s1part[wv][lane] = s1Ar; s1part[wv][16+lane] = s1Br; }
  __syncthreads();
  if (threadIdx.x < 32){
    int t = threadIdx.x;
    float s = s1part[0][t] + s1part[1][t] + s1part[2][t] + s1part[3][t];
    rs1inv[t] = 1.0f / s;
  }
  __syncthreads();

  float* B1 = (float*)(ws + OFF_B1) + (size_t)b*CH*HW;
  float* B2 = (float*)(ws + OFF_B2) + (size_t)b*CH*HW;
  int rl = threadIdx.x & 63;
  int rv = threadIdx.x >> 6;

  #pragma unroll
  for (int v=0; v<16; ++v) red[wv][lane][v] = acc1A[v>>2][v&3];
  __syncthreads();
  #pragma unroll
  for (int k=0;k<4;k++){
    int v = rv + 4*k;
    float s = red[0][rl][v] + red[1][rl][v] + red[2][rl][v] + red[3][rl][v];
    int midx = ((rl>>4)<<2) + (v&3);
    int c = ((v>>2)<<4) + (rl & 15);
    B1[(size_t)c*HW + m0 + midx] = s * rs1inv[midx];
  }
  __syncthreads();
  #pragma unroll
  for (int v=0; v<16; ++v) red[wv][lane][v] = acc2A[v>>2][v&3];
  __syncthreads();
  #pragma unroll
  for (int k=0;k<4;k++){
    int v = rv + 4*k;
    float s = red[0][rl][v] + red[1][rl][v] + red[2][rl][v] + red[3][rl][v];
    int midx = ((rl>>4)<<2) + (v&3);
    int c = ((v>>2)<<4) + (rl & 15);
    B2[(size_t)c*HW + m0 + midx] = s;
  }
  __syncthreads();
  #pragma unroll
  for (int v=0; v<16; ++v) red[wv][lane][v] = acc1B[v>>2][v&3];
  __syncthreads();
  #pragma unroll
  for (int k=0;k<4;k++){
    int v = rv + 4*k;
    float s = red[0][rl][v] + red[1][rl][v] + red[2][rl][v] + red[3][rl][v];
    int midx = ((rl>>4)<<2) + (v&3);
    int c = ((v>>2)<<4) + (rl & 15);
    B1[(size_t)c*HW + m0 + 16 + midx] = s * rs1inv[16 + midx];
  }
  __syncthreads();
  #pragma unroll
  for (int v=0; v<16; ++v) red[wv][lane][v] = acc2B[v>>2][v&3];
  __syncthreads();
  #pragma unroll
  for (int k=0;k<4;k++){
    int v = rv + 4*k;
    float s = red[0][rl][v] + red[1][rl][v] + red[2][rl][v] + red[3][rl][v];
    int midx = ((rl>>4)<<2) + (v&3);
    int c = ((v>>2)<<4) + (rl & 15);
    B2[(size_t)c*HW + m0 + 16 + midx] = s;
  }
}

// ---------------- K4: gate + output convs; register-accumulated ----------------
// 1-D grid 576: b = bid%8 (XCD affinity)
__global__ __launch_bounds__(256) void k_out(
    char* ws,
    const float* gwL, const float* gbL, const float* gwR, const float* gbR,
    const float* wLo, const float* bLoi, const float* wRo, const float* bRoi,
    float* out)
{
  __shared__ float xT[64][64];
  __shared__ float bT[64][64];
  __shared__ float gpart[4][64];
  __shared__ float gLds[64];
  int bid = blockIdx.x;
  int b   = bid & 7;
  int q   = bid >> 3;
  int side= q & 1;
  int p0  = (q >> 1) * 64;
  int t = threadIdx.x;
  const float* braw = (const float*)(ws + (side ? OFF_B2 : OFF_B1)) + (size_t)b*CH*HW;
  const u16*   xc   = (const u16*)(ws + (side ? OFF_XRC : OFF_XLC)) + (size_t)b*CH*HW;
  const float* w    = side ? wRo : wLo;
  const float* gw   = side ? gwR : gwL;
  float        gb   = side ? gbR[0] : gbL[0];
  const float* bias = side ? bRoi : bLoi;

  #pragma unroll
  for (int i=0;i<16;i++){
    int flat = i*256 + t;
    int c = flat >> 6, pl = flat & 63;
    bT[c][pl] = braw[(size_t)c*HW + p0 + pl];
    xT[c][pl] = bf2f(xc[(size_t)c*HW + p0 + pl]);
  }
  __syncthreads();
  {
    int qq = t >> 6, pl = t & 63;
    float a = 0.f;
    #pragma unroll
    for (int c = 0; c < 16; c++) a = fmaf(gw[16*qq + c], bT[16*qq + c][pl], a);
    gpart[qq][pl] = a;
  }
  __syncthreads();
  if (t < 64){
    float x = gpart[0][t]+gpart[1][t]+gpart[2][t]+gpart[3][t] + gb;
    gLds[t] = 1.0f/(1.0f + exp2f(-x*L2E));    // sigmoid
  }
  __syncthreads();
  #pragma unroll
  for (int i=0;i<16;i++){
    int flat = i*256 + t;
    int c = flat >> 6, pl = flat & 63;
    bT[c][pl] *= gLds[pl];
  }
  __syncthreads();
  int wv = t >> 6;
  int lane = t & 63;
  float* outp = out + ((size_t)side*B_ + b)*CH*HW;

  float acc[16];
  #pragma unroll
  for (int oi=0;oi<16;oi++) acc[oi] = bias[wv*16 + oi];
  for (int c=0;c<64;c++){
    float xv = xT[c][lane];
    float bv = bT[c][lane];
    #pragma unroll
    for (int oi=0;oi<16;oi++){
      int o = wv*16 + oi;
      acc[oi] = fmaf(w[(size_t)o*128 + c],      xv, acc[oi]);
      acc[oi] = fmaf(w[(size_t)o*128 + 64 + c], bv, acc[oi]);
    }
  }
  #pragma unroll
  for (int oi=0;oi<16;oi++){
    int o = wv*16 + oi;
    outp[(size_t)o*HW + p0 + lane] = acc[oi];
  }
}

extern "C" void kernel_launch(void* const* d_in, const int* in_sizes, int n_in,
                              void* d_out, int out_size, void* d_ws, size_t ws_size,
                              hipStream_t stream)
{
  char* ws = (char*)d_ws;
  k_proj <<<576, 256, 0, stream>>>(
      (const float*)d_in[0], (const float*)d_in[1],
      (const float*)d_in[2], (const float*)d_in[3],
      (const float*)d_in[4], (const float*)d_in[5],
      (const float*)d_in[6], (const float*)d_in[7], ws);
  k_stats<<<576, 256, 0, stream>>>(ws);
  k_attn <<<576, 256, 0, stream>>>(ws);
  k_out  <<<576, 256, 0, stream>>>(
      ws,
      (const float*)d_in[8],  (const float*)d_in[9],
      (const float*)d_in[10], (const float*)d_in[11],
      (const float*)d_in[12], (const float*)d_in[13],
      (const float*)d_in[14], (const float*)d_in[15],
      (float*)d_out);
}

// Round 20
// 158.656 us; speedup vs baseline: 2.0212x; 1.0237x over previous
//
#include <hip/hip_runtime.h>

typedef unsigned short u16;
typedef __bf16 bf16_t;
typedef bf16_t bf16x8 __attribute__((ext_vector_type(8)));
typedef float f32x4 __attribute__((ext_vector_type(4)));

#define B_   8
#define CH   64
#define HW   2304
#define L2E  1.4426950408889634f

// ---- workspace byte offsets ----
#define OFF_XLC   0u          // bf16 [8][64][2304] channel-major
#define OFF_XRC   2359296u
#define OFF_XLT   4718592u    // bf16 [8][2304][64] position-major
#define OFF_XRT   7077888u
#define OFF_B1    9437184u    // f32  [8][64][2304]
#define OFF_B2    14155776u
#define OFF_RS2   18874368u   // f32  [8][2304]  1/S2[n]
// total 18948096 bytes

__device__ __forceinline__ float bf2f(u16 u){
  union { unsigned int i; float f; } v; v.i = ((unsigned int)u) << 16; return v.f;
}
__device__ __forceinline__ u16 f2bf(float f){
  union { float f; unsigned int i; } v; v.f = f;
  unsigned int r = v.i + 0x7FFFu + ((v.i >> 16) & 1u);
  return (u16)(r >> 16);
}
__device__ __forceinline__ void gload16(const void* g, void* l){
  __builtin_amdgcn_global_load_lds(
      (const __attribute__((address_space(1))) void*)g,
      (__attribute__((address_space(3))) void*)l, 16, 0, 0);
}

// ---------------- K1: xL/xR = W[64x128] @ concat(x_h,x_l) + b ----------------
// r16 form: c-outer streaming x (coalesced VMEM), scalar weight loads, 16 outs/thread.
// 1-D grid 576: b = bid%8 (XCD affinity); q=bid>>3: o0=(q&3)*16, side=(q>>2)&1, p=(q>>3)*256+t
__global__ __launch_bounds__(256) void k_proj(
    const float* xlh, const float* xll, const float* xrh, const float* xrl,
    const float* wLl, const float* bLl, const float* wRr, const float* bRr,
    char* ws)
{
  int bid = blockIdx.x;
  int b   = bid & 7;
  int q   = bid >> 3;
  int o0  = (q & 3) * 16;
  int side= (q >> 2) & 1;
  int p   = (q >> 3) * 256 + threadIdx.x;
  const float* xh = (side ? xrh : xlh) + (size_t)b*CH*HW;
  const float* xl = (side ? xrl : xll) + (size_t)b*CH*HW;
  const float* w  = (side ? wRr : wLl);
  const float* bi = (side ? bRr : bLl);

  float acc[16];
  #pragma unroll
  for (int j=0;j<16;j++) acc[j] = bi[o0+j];
  for (int c=0;c<64;c++){
    float xv = xh[(size_t)c*HW + p];
    #pragma unroll
    for (int j=0;j<16;j++) acc[j] = fmaf(w[(size_t)(o0+j)*128 + c], xv, acc[j]);
  }
  for (int c=0;c<64;c++){
    float xv = xl[(size_t)c*HW + p];
    #pragma unroll
    for (int j=0;j<16;j++) acc[j] = fmaf(w[(size_t)(o0+j)*128 + 64 + c], xv, acc[j]);
  }
  u16* xc = (u16*)(ws + (side ? OFF_XRC : OFF_XLC)) + (size_t)b*CH*HW;
  u16* xt = (u16*)(ws + (side ? OFF_XRT : OFF_XLT)) + (size_t)b*HW*CH;
  unsigned int pk[8];
  #pragma unroll
  for (int j=0;j<8;j++){
    unsigned int lo16 = f2bf(acc[2*j]);
    unsigned int hi16 = f2bf(acc[2*j+1]);
    pk[j] = lo16 | (hi16 << 16);
    xc[(size_t)(o0+2*j  )*HW + p] = (u16)lo16;
    xc[(size_t)(o0+2*j+1)*HW + p] = (u16)hi16;
  }
  uint4* dst = (uint4*)&xt[(size_t)p*CH + o0];
  dst[0] = make_uint4(pk[0],pk[1],pk[2],pk[3]);
  dst[1] = make_uint4(pk[4],pk[5],pk[6],pk[7]);
}

// ---------------- K2: 1/S2[n]; 32 A-rows/block (regs), LDS-staged Y tiles ----------------
// 1-D grid 576: b = bid%8; r0 = (bid/8)*32; wave wv: m-cols [wv*576,+576) as 2 streams
__global__ __launch_bounds__(256, 4) void k_stats(char* ws)
{
  __shared__ alignas(16) char smraw[16384];   // 4KB per wave: P tile 2KB + Q tile 2KB
  __shared__ float part[4][2][4][4];
  int bid = blockIdx.x;
  int b   = bid & 7;
  int r0  = (bid >> 3) * 32;
  const char* Xb = ws + OFF_XLT + (size_t)b*HW*CH*2;   // rows n (A operand, regs)
  const char* Yb = ws + OFF_XRT + (size_t)b*HW*CH*2;   // reduce over m (staged)
  float* out = (float*)(ws + OFF_RS2) + b*HW;

  int lane = threadIdx.x & 63;
  int wv   = __builtin_amdgcn_readfirstlane(threadIdx.x >> 6);
  int lo = lane & 15, g = lane >> 4;
  int l = lane;

  const u16* Xu = (const u16*)Xb;
  bf16x8 aA0 = *(const bf16x8*)&Xu[(size_t)(r0+lo)*CH + 8*g];
  bf16x8 aA1 = *(const bf16x8*)&Xu[(size_t)(r0+lo)*CH + 32 + 8*g];
  bf16x8 aB0 = *(const bf16x8*)&Xu[(size_t)(r0+16+lo)*CH + 8*g];
  bf16x8 aB1 = *(const bf16x8*)&Xu[(size_t)(r0+16+lo)*CH + 32 + 8*g];

  // stage source offsets: inst j covers rows j*8..j*8+7; s(r)=r&7
  int ySrc[2];
  #pragma unroll
  for (int j=0;j<2;j++){
    int r = j*8 + (l>>3);
    ySrc[j] = r*128 + (((l&7) ^ (r&7)))*16;
  }
  char* myY = smraw + wv*4096;
  int jbP = wv*576, jbQ = jbP + 288;

  // read offsets: row lo, slot g / 4|g, s(lo)=lo&7
  int rdP0 = lo*128 + ((g      ^ (lo&7)))*16;
  int rdP1 = lo*128 + (((4|g)  ^ (lo&7)))*16;

  #define STAGE_S(i) do { \
    const char* gp = Yb + (size_t)(jbP + (i)*16)*128; \
    const char* gq = Yb + (size_t)(jbQ + (i)*16)*128; \
    gload16(gp + ySrc[0], myY + 0);    gload16(gp + ySrc[1], myY + 1024); \
    gload16(gq + ySrc[0], myY + 2048); gload16(gq + ySrc[1], myY + 3072); \
  } while(0)

  float sPA[4] = {0.f,0.f,0.f,0.f};
  float sQA[4] = {0.f,0.f,0.f,0.f};
  float sPB[4] = {0.f,0.f,0.f,0.f};
  float sQB[4] = {0.f,0.f,0.f,0.f};

  STAGE_S(0);
  for (int i = 0; i < 18; ++i){
    asm volatile("s_waitcnt vmcnt(0)" ::: "memory");
    __builtin_amdgcn_sched_barrier(0);
    bf16x8 bP0 = *(const bf16x8*)(myY + rdP0);
    bf16x8 bP1 = *(const bf16x8*)(myY + rdP1);
    bf16x8 bQ0 = *(const bf16x8*)(myY + 2048 + rdP0);
    bf16x8 bQ1 = *(const bf16x8*)(myY + 2048 + rdP1);
    asm volatile("s_waitcnt lgkmcnt(0)" ::: "memory");
    __builtin_amdgcn_sched_barrier(0);
    int inext = (i+1 < 18) ? i+1 : 0;
    STAGE_S(inext);
    __builtin_amdgcn_sched_barrier(0);
    f32x4 z4 = {0.f,0.f,0.f,0.f};
    f32x4 dPA = __builtin_amdgcn_mfma_f32_16x16x32_bf16(aA0, bP0, z4, 0,0,0);
    dPA = __builtin_amdgcn_mfma_f32_16x16x32_bf16(aA1, bP1, dPA, 0,0,0);
    f32x4 dQA = __builtin_amdgcn_mfma_f32_16x16x32_bf16(aA0, bQ0, z4, 0,0,0);
    dQA = __builtin_amdgcn_mfma_f32_16x16x32_bf16(aA1, bQ1, dQA, 0,0,0);
    f32x4 dPB = __builtin_amdgcn_mfma_f32_16x16x32_bf16(aB0, bP0, z4, 0,0,0);
    dPB = __builtin_amdgcn_mfma_f32_16x16x32_bf16(aB1, bP1, dPB, 0,0,0);
    f32x4 dQB = __builtin_amdgcn_mfma_f32_16x16x32_bf16(aB0, bQ0, z4, 0,0,0);
    dQB = __builtin_amdgcn_mfma_f32_16x16x32_bf16(aB1, bQ1, dQB, 0,0,0);
    #pragma unroll
    for (int r=0;r<4;r++){
      sPA[r] += exp2f(dPA[r]*L2E); sQA[r] += exp2f(dQA[r]*L2E);
      sPB[r] += exp2f(dPB[r]*L2E); sQB[r] += exp2f(dQB[r]*L2E);
    }
  }
  #undef STAGE_S
  float sA[4], sB[4];
  #pragma unroll
  for (int r=0;r<4;r++){ sA[r] = sPA[r] + sQA[r]; sB[r] = sPB[r] + sQB[r]; }
  #pragma unroll
  for (int mask = 1; mask < 16; mask <<= 1){
    #pragma unroll
    for (int r=0;r<4;r++){
      sA[r] += __shfl_xor(sA[r], mask, 64);
      sB[r] += __shfl_xor(sB[r], mask, 64);
    }
  }
  if (lo == 0){
    #pragma unroll
    for (int r=0;r<4;r++){ part[wv][0][g][r] = sA[r]; part[wv][1][g][r] = sB[r]; }
  }
  __syncthreads();
  if (threadIdx.x < 32){
    int t = threadIdx.x;
    int half = t >> 4, gg = (t & 15) >> 2, rr = t & 3;
    float sum = part[0][half][gg][rr] + part[1][half][gg][rr]
              + part[2][half][gg][rr] + part[3][half][gg][rr];
    out[r0 + 16*half + 4*gg + rr] = 1.0f / sum;
  }
}

// ---------------- K3: fused aff->P -> b1^T/b2^T; LDS-staged, per-wave private ----------------
// 1-D grid 576: b = bid%8; m0 = (bid/8)*32; wave wv: n-quarter, 18 steps of 32
// Epilogue writes COALESCED: thread -> (c, mm) with 16 consecutive m per c-row.
__global__ __launch_bounds__(256, 3) void k_attn(char* ws)
{
  __shared__ alignas(16) char smraw[49152];   // 12KB/wave: A 4KB | BL 4KB | BR 4KB
  int bid  = blockIdx.x;
  int b    = bid & 7;
  int m0   = (bid >> 3) * 32;
  int lane = threadIdx.x & 63;
  int wv   = __builtin_amdgcn_readfirstlane(threadIdx.x >> 6);
  int lo = lane & 15, g = lane >> 4;
  int l = lane;

  const char* XLt = ws + OFF_XLT + (size_t)b*HW*CH*2;
  const char* XRt = ws + OFF_XRT + (size_t)b*HW*CH*2;
  const char* XLc = ws + OFF_XLC + (size_t)b*CH*HW*2;
  const char* XRc = ws + OFF_XRC + (size_t)b*CH*HW*2;
  const float* rs2 = (const float*)(ws + OFF_RS2) + b*HW;

  const u16* XRtu = (const u16*)XRt;
  bf16x8 fmA0 = *(const bf16x8*)&XRtu[(size_t)(m0+lo)*CH + 8*g];
  bf16x8 fmA1 = *(const bf16x8*)&XRtu[(size_t)(m0+lo)*CH + 32 + 8*g];
  bf16x8 fmB0 = *(const bf16x8*)&XRtu[(size_t)(m0+16+lo)*CH + 8*g];
  bf16x8 fmB1 = *(const bf16x8*)&XRtu[(size_t)(m0+16+lo)*CH + 32 + 8*g];

  // ---- stage source offsets (pre-swizzled global addresses) ----
  int aSrc[4], bSrc[4];
  #pragma unroll
  for (int j=0;j<4;j++){
    int r  = j*8 + (l>>3);
    int sa = (r&3) | (((r>>3)&1)<<2);
    aSrc[j] = r*128 + (((l&7) ^ sa))*16;            // + n0*128
    int c  = j*16 + (l>>2);
    int sb = (c>>1)&3;
    bSrc[j] = c*(HW*2) + (((l&3) ^ sb))*16;         // + n0*2
  }
  char* myA  = smraw + wv*12288;
  char* myBL = myA + 4096;
  char* myBR = myA + 8192;

  // ---- read offsets ----
  int pr  = ((lo>>2)<<3) + (lo&3);
  int sAr = (lo&3) | (((lo>>2)&1)<<2);
  int rdA00 = pr*128     + ((g     ^ sAr))*16;
  int rdA01 = pr*128     + (((4|g) ^ sAr))*16;
  int rdA10 = (pr+4)*128 + ((g     ^ sAr))*16;
  int rdA11 = (pr+4)*128 + (((4|g) ^ sAr))*16;
  int sBr = (lo>>1)&3;
  int rdB0 = (     lo)*64 + ((g ^ sBr))*16;
  int rdB1 = (16 + lo)*64 + ((g ^ sBr))*16;
  int rdB2 = (32 + lo)*64 + ((g ^ sBr))*16;
  int rdB3 = (48 + lo)*64 + ((g ^ sBr))*16;

  #define STAGE_A(n0v) do { \
    const char* gA = XLt + (size_t)(n0v)*128; \
    const char* gL = XLc + (size_t)(n0v)*2; \
    const char* gR = XRc + (size_t)(n0v)*2; \
    gload16(gA + aSrc[0], myA  + 0);    gload16(gA + aSrc[1], myA  + 1024); \
    gload16(gA + aSrc[2], myA  + 2048); gload16(gA + aSrc[3], myA  + 3072); \
    gload16(gL + bSrc[0], myBL + 0);    gload16(gL + bSrc[1], myBL + 1024); \
    gload16(gL + bSrc[2], myBL + 2048); gload16(gL + bSrc[3], myBL + 3072); \
    gload16(gR + bSrc[0], myBR + 0);    gload16(gR + bSrc[1], myBR + 1024); \
    gload16(gR + bSrc[2], myBR + 2048); gload16(gR + bSrc[3], myBR + 3072); \
  } while(0)

  f32x4 acc1A[4], acc2A[4], acc1B[4], acc2B[4];
  #pragma unroll
  for (int ct=0;ct<4;ct++){
    f32x4 z4 = {0.f,0.f,0.f,0.f};
    acc1A[ct]=z4; acc2A[ct]=z4; acc1B[ct]=z4; acc2B[ct]=z4;
  }
  float s1A = 0.f, s1B = 0.f;

  int nbeg = wv * 576;
  STAGE_A(nbeg);
  for (int s = 0; s < 18; ++s){
    int n0 = nbeg + s*32;
    asm volatile("s_waitcnt vmcnt(0)" ::: "memory");
    __builtin_amdgcn_sched_barrier(0);
    bf16x8 fa00 = *(const bf16x8*)(myA + rdA00);
    bf16x8 fa01 = *(const bf16x8*)(myA + rdA01);
    bf16x8 fa10 = *(const bf16x8*)(myA + rdA10);
    bf16x8 fa11 = *(const bf16x8*)(myA + rdA11);
    bf16x8 bL0 = *(const bf16x8*)(myBL + rdB0);
    bf16x8 bL1 = *(const bf16x8*)(myBL + rdB1);
    bf16x8 bL2 = *(const bf16x8*)(myBL + rdB2);
    bf16x8 bL3 = *(const bf16x8*)(myBL + rdB3);
    bf16x8 bR0 = *(const bf16x8*)(myBR + rdB0);
    bf16x8 bR1 = *(const bf16x8*)(myBR + rdB1);
    bf16x8 bR2 = *(const bf16x8*)(myBR + rdB2);
    bf16x8 bR3 = *(const bf16x8*)(myBR + rdB3);
    f32x4 r20 = *(const f32x4*)&rs2[n0 + 8*g];
    f32x4 r21 = *(const f32x4*)&rs2[n0 + 8*g + 4];
    asm volatile("s_waitcnt lgkmcnt(0)" ::: "memory");
    __builtin_amdgcn_sched_barrier(0);
    int n1 = (s+1 < 18) ? n0 + 32 : nbeg;
    STAGE_A(n1);
    __builtin_amdgcn_sched_barrier(0);

    f32x4 z4 = {0.f,0.f,0.f,0.f};
    f32x4 d0A = __builtin_amdgcn_mfma_f32_16x16x32_bf16(fa00, fmA0, z4, 0,0,0);
    d0A = __builtin_amdgcn_mfma_f32_16x16x32_bf16(fa01, fmA1, d0A, 0,0,0);
    f32x4 d1A = __builtin_amdgcn_mfma_f32_16x16x32_bf16(fa10, fmA0, z4, 0,0,0);
    d1A = __builtin_amdgcn_mfma_f32_16x16x32_bf16(fa11, fmA1, d1A, 0,0,0);
    f32x4 d0B = __builtin_amdgcn_mfma_f32_16x16x32_bf16(fa00, fmB0, z4, 0,0,0);
    d0B = __builtin_amdgcn_mfma_f32_16x16x32_bf16(fa01, fmB1, d0B, 0,0,0);
    f32x4 d1B = __builtin_amdgcn_mfma_f32_16x16x32_bf16(fa10, fmB0, z4, 0,0,0);
    d1B = __builtin_amdgcn_mfma_f32_16x16x32_bf16(fa11, fmB1, d1B, 0,0,0);

    bf16x8 pa1A, pa2A, pa1B, pa2B;
    #pragma unroll
    for (int r=0;r<4;r++){
      float e0 = exp2f(d0A[r]*L2E);
      float e1 = exp2f(d1A[r]*L2E);
      s1A += e0 + e1;
      pa1A[r]   = (bf16_t)e0;
      pa1A[r+4] = (bf16_t)e1;
      pa2A[r]   = (bf16_t)(e0 * r20[r]);
      pa2A[r+4] = (bf16_t)(e1 * r21[r]);
      float f0 = exp2f(d0B[r]*L2E);
      float f1 = exp2f(d1B[r]*L2E);
      s1B += f0 + f1;
      pa1B[r]   = (bf16_t)f0;
      pa1B[r+4] = (bf16_t)f1;
      pa2B[r]   = (bf16_t)(f0 * r20[r]);
      pa2B[r+4] = (bf16_t)(f1 * r21[r]);
    }
    acc1A[0] = __builtin_amdgcn_mfma_f32_16x16x32_bf16(pa1A, bL0, acc1A[0], 0,0,0);
    acc1A[1] = __builtin_amdgcn_mfma_f32_16x16x32_bf16(pa1A, bL1, acc1A[1], 0,0,0);
    acc1A[2] = __builtin_amdgcn_mfma_f32_16x16x32_bf16(pa1A, bL2, acc1A[2], 0,0,0);
    acc1A[3] = __builtin_amdgcn_mfma_f32_16x16x32_bf16(pa1A, bL3, acc1A[3], 0,0,0);
    acc2A[0] = __builtin_amdgcn_mfma_f32_16x16x32_bf16(pa2A, bR0, acc2A[0], 0,0,0);
    acc2A[1] = __builtin_amdgcn_mfma_f32_16x16x32_bf16(pa2A, bR1, acc2A[1], 0,0,0);
    acc2A[2] = __builtin_amdgcn_mfma_f32_16x16x32_bf16(pa2A, bR2, acc2A[2], 0,0,0);
    acc2A[3] = __builtin_amdgcn_mfma_f32_16x16x32_bf16(pa2A, bR3, acc2A[3], 0,0,0);
    acc1B[0] = __builtin_amdgcn_mfma_f32_16x16x32_bf16(pa1B, bL0, acc1B[0], 0,0,0);
    acc1B[1] = __builtin_amdgcn_mfma_f32_16x16x32_bf16(pa1B, bL1, acc1B[1], 0,0,0);
    acc1B[2] = __builtin_amdgcn_mfma_f32_16x16x32_bf16(pa1B, bL2, acc1B[2], 0,0,0);
    acc1B[3] = __builtin_amdgcn_mfma_f32_16x16x32_bf16(pa1B, bL3, acc1B[3], 0,0,0);
    acc2B[0] = __builtin_amdgcn_mfma_f32_16x16x32_bf16(pa2B, bR0, acc2B[0], 0,0,0);
    acc2B[1] = __builtin_amdgcn_mfma_f32_16x16x32_bf16(pa2B, bR1, acc2B[1], 0,0,0);
    acc2B[2] = __builtin_amdgcn_mfma_f32_16x16x32_bf16(pa2B, bR2, acc2B[2], 0,0,0);
    acc2B[3] = __builtin_amdgcn_mfma_f32_16x16x32_bf16(pa2B, bR3, acc2B[3], 0,0,0);
  }
  #undef STAGE_A

  // protect overlay: all waves must finish their staged loop before red[] reuse
  asm volatile("s_waitcnt vmcnt(0)" ::: "memory");
  __syncthreads();

  float (*red)[64][17] = (float (*)[64][17])smraw;                 // 17408 B
  float (*s1part)[32]  = (float (*)[32])(smraw + 17408);           // 512 B
  float* rs1inv        = (float*)(smraw + 17920);                  // 128 B

  // ---- S1 block reduction ----
  float s1Ar = s1A + __shfl_xor(s1A, 16, 64);
  s1Ar += __shfl_xor(s1Ar, 32, 64);
  float s1Br = s1B + __shfl_xor(s1B, 16, 64);
  s1Br += __shfl_xor(s1Br, 32, 64);
  if (lane < 16){ s1part[wv][lane] = s1Ar; s1part[wv][16+lane] = s1Br; }
  __syncthreads();
  if (threadIdx.x < 32){
    int t = threadIdx.x;
    float s = s1part[0][t] + s1part[1][t] + s1part[2][t] + s1part[3][t];
    rs1inv[t] = 1.0f / s;
  }
  __syncthreads();

  float* B1 = (float*)(ws + OFF_B1) + (size_t)b*CH*HW;
  float* B2 = (float*)(ws + OFF_B2) + (size_t)b*CH*HW;
  int tt = threadIdx.x;

  // Coalesced write mapping: thread -> (c = tt>>4 + 16*pass, mm = tt&15);
  // inverse of red layout: value(c,mm) lives at v = ((c>>4)<<2)+(mm&3),
  // l = (c&15)+((mm>>2)<<4).  16 consecutive lanes write 64 contiguous bytes.
  #define RED_WRITE(DST, MBASE, SCALE) do { \
    _Pragma("unroll") \
    for (int pass=0; pass<4; ++pass){ \
      int c  = (tt>>4) + pass*16; \
      int mm = tt & 15; \
      int v  = ((c>>4)<<2) + (mm&3); \
      int ll = (c&15) + ((mm>>2)<<4); \
      float s = red[0][ll][v] + red[1][ll][v] + red[2][ll][v] + red[3][ll][v]; \
      DST[(size_t)c*HW + m0 + (MBASE) + mm] = s * (SCALE); \
    } \
  } while(0)

  #pragma unroll
  for (int v=0; v<16; ++v) red[wv][lane][v] = acc1A[v>>2][v&3];
  __syncthreads();
  RED_WRITE(B1, 0, rs1inv[tt & 15]);
  __syncthreads();
  #pragma unroll
  for (int v=0; v<16; ++v) red[wv][lane][v] = acc2A[v>>2][v&3];
  __syncthreads();
  RED_WRITE(B2, 0, 1.0f);
  __syncthreads();
  #pragma unroll
  for (int v=0; v<16; ++v) red[wv][lane][v] = acc1B[v>>2][v&3];
  __syncthreads();
  RED_WRITE(B1, 16, rs1inv[16 + (tt & 15)]);
  __syncthreads();
  #pragma unroll
  for (int v=0; v<16; ++v) red[wv][lane][v] = acc2B[v>>2][v&3];
  __syncthreads();
  RED_WRITE(B2, 16, 1.0f);
  #undef RED_WRITE
}

// ---------------- K4: gate + output convs; register-accumulated ----------------
// 1-D grid 576: b = bid%8 (XCD affinity)
__global__ __launch_bounds__(256) void k_out(
    char* ws,
    const float* gwL, const float* gbL, const float* gwR, const float* gbR,
    const float* wLo, const float* bLoi, const float* wRo, const float* bRoi,
    float* out)
{
  __shared__ float xT[64][64];
  __shared__ float bT[64][64];
  __shared__ float gpart[4][64];
  __shared__ float gLds[64];
  int bid = blockIdx.x;
  int b   = bid & 7;
  int q   = bid >> 3;
  int side= q & 1;
  int p0  = (q >> 1) * 64;
  int t = threadIdx.x;
  const float* braw = (const float*)(ws + (side ? OFF_B2 : OFF_B1)) + (size_t)b*CH*HW;
  const u16*   xc   = (const u16*)(ws + (side ? OFF_XRC : OFF_XLC)) + (size_t)b*CH*HW;
  const float* w    = side ? wRo : wLo;
  const float* gw   = side ? gwR : gwL;
  float        gb   = side ? gbR[0] : gbL[0];
  const float* bias = side ? bRoi : bLoi;

  #pragma unroll
  for (int i=0;i<16;i++){
    int flat = i*256 + t;
    int c = flat >> 6, pl = flat & 63;
    bT[c][pl] = braw[(size_t)c*HW + p0 + pl];
    xT[c][pl] = bf2f(xc[(size_t)c*HW + p0 + pl]);
  }
  __syncthreads();
  {
    int qq = t >> 6, pl = t & 63;
    float a = 0.f;
    #pragma unroll
    for (int c = 0; c < 16; c++) a = fmaf(gw[16*qq + c], bT[16*qq + c][pl], a);
    gpart[qq][pl] = a;
  }
  __syncthreads();
  if (t < 64){
    float x = gpart[0][t]+gpart[1][t]+gpart[2][t]+gpart[3][t] + gb;
    gLds[t] = 1.0f/(1.0f + exp2f(-x*L2E));    // sigmoid
  }
  __syncthreads();
  #pragma unroll
  for (int i=0;i<16;i++){
    int flat = i*256 + t;
    int c = flat >> 6, pl = flat & 63;
    bT[c][pl] *= gLds[pl];
  }
  __syncthreads();
  int wv = t >> 6;
  int lane = t & 63;
  float* outp = out + ((size_t)side*B_ + b)*CH*HW;

  float acc[16];
  #pragma unroll
  for (int oi=0;oi<16;oi++) acc[oi] = bias[wv*16 + oi];
  for (int c=0;c<64;c++){
    float xv = xT[c][lane];
    float bv = bT[c][lane];
    #pragma unroll
    for (int oi=0;oi<16;oi++){
      int o = wv*16 + oi;
      acc[oi] = fmaf(w[(size_t)o*128 + c],      xv, acc[oi]);
      acc[oi] = fmaf(w[(size_t)o*128 + 64 + c], bv, acc[oi]);
    }
  }
  #pragma unroll
  for (int oi=0;oi<16;oi++){
    int o = wv*16 + oi;
    outp[(size_t)o*HW + p0 + lane] = acc[oi];
  }
}

extern "C" void kernel_launch(void* const* d_in, const int* in_sizes, int n_in,
                              void* d_out, int out_size, void* d_ws, size_t ws_size,
                              hipStream_t stream)
{
  char* ws = (char*)d_ws;
  k_proj <<<576, 256, 0, stream>>>(
      (const float*)d_in[0], (const float*)d_in[1],
      (const float*)d_in[2], (const float*)d_in[3],
      (const float*)d_in[4], (const float*)d_in[5],
      (const float*)d_in[6], (const float*)d_in[7], ws);
  k_stats<<<576, 256, 0, stream>>>(ws);
  k_attn <<<576, 256, 0, stream>>>(ws);
  k_out  <<<576, 256, 0, stream>>>(
      ws,
      (const float*)d_in[8],  (const float*)d_in[9],
      (const float*)d_in[10], (const float*)d_in[11],
      (const float*)d_in[12], (const float*)d_in[13],
      (const float*)d_in[14], (const float*)d_in[15],
      (float*)d_out);
}

// Round 21
// 150.227 us; speedup vs baseline: 2.1346x; 1.0561x over previous
//
#include <hip/hip_runtime.h>

typedef unsigned short u16;
typedef __bf16 bf16_t;
typedef bf16_t bf16x8 __attribute__((ext_vector_type(8)));
typedef float f32x4 __attribute__((ext_vector_type(4)));

#define B_   8
#define CH   64
#define HW   2304
#define L2E  1.4426950408889634f

// ---- workspace byte offsets ----
#define OFF_XLC   0u          // bf16 [8][64][2304] channel-major
#define OFF_XRC   2359296u
#define OFF_XLT   4718592u    // bf16 [8][2304][64] position-major
#define OFF_XRT   7077888u
#define OFF_RS2   18874368u   // f32  [8][2304]  1/S2[n]   (B1/B2 no longer needed)

__device__ __forceinline__ float bf2f(u16 u){
  union { unsigned int i; float f; } v; v.i = ((unsigned int)u) << 16; return v.f;
}
__device__ __forceinline__ u16 f2bf(float f){
  union { float f; unsigned int i; } v; v.f = f;
  unsigned int r = v.i + 0x7FFFu + ((v.i >> 16) & 1u);
  return (u16)(r >> 16);
}
__device__ __forceinline__ void gload16(const void* g, void* l){
  __builtin_amdgcn_global_load_lds(
      (const __attribute__((address_space(1))) void*)g,
      (__attribute__((address_space(3))) void*)l, 16, 0, 0);
}

// ---------------- K1: xL/xR = W[64x128] @ concat(x_h,x_l) + b ----------------
// 1-D grid 576: b = bid%8 (XCD affinity); q=bid>>3: o0=(q&3)*16, side=(q>>2)&1, p=(q>>3)*256+t
__global__ __launch_bounds__(256) void k_proj(
    const float* xlh, const float* xll, const float* xrh, const float* xrl,
    const float* wLl, const float* bLl, const float* wRr, const float* bRr,
    char* ws)
{
  int bid = blockIdx.x;
  int b   = bid & 7;
  int q   = bid >> 3;
  int o0  = (q & 3) * 16;
  int side= (q >> 2) & 1;
  int p   = (q >> 3) * 256 + threadIdx.x;
  const float* xh = (side ? xrh : xlh) + (size_t)b*CH*HW;
  const float* xl = (side ? xrl : xll) + (size_t)b*CH*HW;
  const float* w  = (side ? wRr : wLl);
  const float* bi = (side ? bRr : bLl);

  float acc[16];
  #pragma unroll
  for (int j=0;j<16;j++) acc[j] = bi[o0+j];
  for (int c=0;c<64;c++){
    float xv = xh[(size_t)c*HW + p];
    #pragma unroll
    for (int j=0;j<16;j++) acc[j] = fmaf(w[(size_t)(o0+j)*128 + c], xv, acc[j]);
  }
  for (int c=0;c<64;c++){
    float xv = xl[(size_t)c*HW + p];
    #pragma unroll
    for (int j=0;j<16;j++) acc[j] = fmaf(w[(size_t)(o0+j)*128 + 64 + c], xv, acc[j]);
  }
  u16* xc = (u16*)(ws + (side ? OFF_XRC : OFF_XLC)) + (size_t)b*CH*HW;
  u16* xt = (u16*)(ws + (side ? OFF_XRT : OFF_XLT)) + (size_t)b*HW*CH;
  unsigned int pk[8];
  #pragma unroll
  for (int j=0;j<8;j++){
    unsigned int lo16 = f2bf(acc[2*j]);
    unsigned int hi16 = f2bf(acc[2*j+1]);
    pk[j] = lo16 | (hi16 << 16);
    xc[(size_t)(o0+2*j  )*HW + p] = (u16)lo16;
    xc[(size_t)(o0+2*j+1)*HW + p] = (u16)hi16;
  }
  uint4* dst = (uint4*)&xt[(size_t)p*CH + o0];
  dst[0] = make_uint4(pk[0],pk[1],pk[2],pk[3]);
  dst[1] = make_uint4(pk[4],pk[5],pk[6],pk[7]);
}

// ---------------- K2: 1/S2[n]; 32 A-rows/block (regs), LDS-staged Y tiles ----------------
__global__ __launch_bounds__(256, 4) void k_stats(char* ws)
{
  __shared__ alignas(16) char smraw[16384];
  __shared__ float part[4][2][4][4];
  int bid = blockIdx.x;
  int b   = bid & 7;
  int r0  = (bid >> 3) * 32;
  const char* Xb = ws + OFF_XLT + (size_t)b*HW*CH*2;
  const char* Yb = ws + OFF_XRT + (size_t)b*HW*CH*2;
  float* out = (float*)(ws + OFF_RS2) + b*HW;

  int lane = threadIdx.x & 63;
  int wv   = __builtin_amdgcn_readfirstlane(threadIdx.x >> 6);
  int lo = lane & 15, g = lane >> 4;
  int l = lane;

  const u16* Xu = (const u16*)Xb;
  bf16x8 aA0 = *(const bf16x8*)&Xu[(size_t)(r0+lo)*CH + 8*g];
  bf16x8 aA1 = *(const bf16x8*)&Xu[(size_t)(r0+lo)*CH + 32 + 8*g];
  bf16x8 aB0 = *(const bf16x8*)&Xu[(size_t)(r0+16+lo)*CH + 8*g];
  bf16x8 aB1 = *(const bf16x8*)&Xu[(size_t)(r0+16+lo)*CH + 32 + 8*g];

  int ySrc[2];
  #pragma unroll
  for (int j=0;j<2;j++){
    int r = j*8 + (l>>3);
    ySrc[j] = r*128 + (((l&7) ^ (r&7)))*16;
  }
  char* myY = smraw + wv*4096;
  int jbP = wv*576, jbQ = jbP + 288;

  int rdP0 = lo*128 + ((g      ^ (lo&7)))*16;
  int rdP1 = lo*128 + (((4|g)  ^ (lo&7)))*16;

  #define STAGE_S(i) do { \
    const char* gp = Yb + (size_t)(jbP + (i)*16)*128; \
    const char* gq = Yb + (size_t)(jbQ + (i)*16)*128; \
    gload16(gp + ySrc[0], myY + 0);    gload16(gp + ySrc[1], myY + 1024); \
    gload16(gq + ySrc[0], myY + 2048); gload16(gq + ySrc[1], myY + 3072); \
  } while(0)

  float sPA[4] = {0.f,0.f,0.f,0.f};
  float sQA[4] = {0.f,0.f,0.f,0.f};
  float sPB[4] = {0.f,0.f,0.f,0.f};
  float sQB[4] = {0.f,0.f,0.f,0.f};

  STAGE_S(0);
  for (int i = 0; i < 18; ++i){
    asm volatile("s_waitcnt vmcnt(0)" ::: "memory");
    __builtin_amdgcn_sched_barrier(0);
    bf16x8 bP0 = *(const bf16x8*)(myY + rdP0);
    bf16x8 bP1 = *(const bf16x8*)(myY + rdP1);
    bf16x8 bQ0 = *(const bf16x8*)(myY + 2048 + rdP0);
    bf16x8 bQ1 = *(const bf16x8*)(myY + 2048 + rdP1);
    asm volatile("s_waitcnt lgkmcnt(0)" ::: "memory");
    __builtin_amdgcn_sched_barrier(0);
    int inext = (i+1 < 18) ? i+1 : 0;
    STAGE_S(inext);
    __builtin_amdgcn_sched_barrier(0);
    f32x4 z4 = {0.f,0.f,0.f,0.f};
    f32x4 dPA = __builtin_amdgcn_mfma_f32_16x16x32_bf16(aA0, bP0, z4, 0,0,0);
    dPA = __builtin_amdgcn_mfma_f32_16x16x32_bf16(aA1, bP1, dPA, 0,0,0);
    f32x4 dQA = __builtin_amdgcn_mfma_f32_16x16x32_bf16(aA0, bQ0, z4, 0,0,0);
    dQA = __builtin_amdgcn_mfma_f32_16x16x32_bf16(aA1, bQ1, dQA, 0,0,0);
    f32x4 dPB = __builtin_amdgcn_mfma_f32_16x16x32_bf16(aB0, bP0, z4, 0,0,0);
    dPB = __builtin_amdgcn_mfma_f32_16x16x32_bf16(aB1, bP1, dPB, 0,0,0);
    f32x4 dQB = __builtin_amdgcn_mfma_f32_16x16x32_bf16(aB0, bQ0, z4, 0,0,0);
    dQB = __builtin_amdgcn_mfma_f32_16x16x32_bf16(aB1, bQ1, dQB, 0,0,0);
    #pragma unroll
    for (int r=0;r<4;r++){
      sPA[r] += exp2f(dPA[r]*L2E); sQA[r] += exp2f(dQA[r]*L2E);
      sPB[r] += exp2f(dPB[r]*L2E); sQB[r] += exp2f(dQB[r]*L2E);
    }
  }
  #undef STAGE_S
  float sA[4], sB[4];
  #pragma unroll
  for (int r=0;r<4;r++){ sA[r] = sPA[r] + sQA[r]; sB[r] = sPB[r] + sQB[r]; }
  #pragma unroll
  for (int mask = 1; mask < 16; mask <<= 1){
    #pragma unroll
    for (int r=0;r<4;r++){
      sA[r] += __shfl_xor(sA[r], mask, 64);
      sB[r] += __shfl_xor(sB[r], mask, 64);
    }
  }
  if (lo == 0){
    #pragma unroll
    for (int r=0;r<4;r++){ part[wv][0][g][r] = sA[r]; part[wv][1][g][r] = sB[r]; }
  }
  __syncthreads();
  if (threadIdx.x < 32){
    int t = threadIdx.x;
    int half = t >> 4, gg = (t & 15) >> 2, rr = t & 3;
    float sum = part[0][half][gg][rr] + part[1][half][gg][rr]
              + part[2][half][gg][rr] + part[3][half][gg][rr];
    out[r0 + 16*half + 4*gg + rr] = 1.0f / sum;
  }
}

// ---------------- K3: FUSED aff->P -> b1/b2 -> gate -> output convs ----------------
// 1-D grid 576: b = bid%8; m0 = (bid/8)*32; wave wv: n-quarter, 18 steps of 32.
// Epilogue: reduce into LDS tiles, gate+sigmoid, scale, output conv, final store.
__global__ __launch_bounds__(256, 3) void k_attn(
    char* ws,
    const float* gwL, const float* gbL, const float* gwR, const float* gbR,
    const float* wLo, const float* bLo, const float* wRo, const float* bRo,
    float* outp)
{
  __shared__ alignas(16) char smraw[49152];
  int bid  = blockIdx.x;
  int b    = bid & 7;
  int m0   = (bid >> 3) * 32;
  int lane = threadIdx.x & 63;
  int wv   = __builtin_amdgcn_readfirstlane(threadIdx.x >> 6);
  int lo = lane & 15, g = lane >> 4;
  int l = lane;

  const char* XLt = ws + OFF_XLT + (size_t)b*HW*CH*2;
  const char* XRt = ws + OFF_XRT + (size_t)b*HW*CH*2;
  const char* XLc = ws + OFF_XLC + (size_t)b*CH*HW*2;
  const char* XRc = ws + OFF_XRC + (size_t)b*CH*HW*2;
  const float* rs2 = (const float*)(ws + OFF_RS2) + b*HW;

  const u16* XRtu = (const u16*)XRt;
  bf16x8 fmA0 = *(const bf16x8*)&XRtu[(size_t)(m0+lo)*CH + 8*g];
  bf16x8 fmA1 = *(const bf16x8*)&XRtu[(size_t)(m0+lo)*CH + 32 + 8*g];
  bf16x8 fmB0 = *(const bf16x8*)&XRtu[(size_t)(m0+16+lo)*CH + 8*g];
  bf16x8 fmB1 = *(const bf16x8*)&XRtu[(size_t)(m0+16+lo)*CH + 32 + 8*g];

  int aSrc[4], bSrc[4];
  #pragma unroll
  for (int j=0;j<4;j++){
    int r  = j*8 + (l>>3);
    int sa = (r&3) | (((r>>3)&1)<<2);
    aSrc[j] = r*128 + (((l&7) ^ sa))*16;
    int c  = j*16 + (l>>2);
    int sb = (c>>1)&3;
    bSrc[j] = c*(HW*2) + (((l&3) ^ sb))*16;
  }
  char* myA  = smraw + wv*12288;
  char* myBL = myA + 4096;
  char* myBR = myA + 8192;

  int pr  = ((lo>>2)<<3) + (lo&3);
  int sAr = (lo&3) | (((lo>>2)&1)<<2);
  int rdA00 = pr*128     + ((g     ^ sAr))*16;
  int rdA01 = pr*128     + (((4|g) ^ sAr))*16;
  int rdA10 = (pr+4)*128 + ((g     ^ sAr))*16;
  int rdA11 = (pr+4)*128 + (((4|g) ^ sAr))*16;
  int sBr = (lo>>1)&3;
  int rdB0 = (     lo)*64 + ((g ^ sBr))*16;
  int rdB1 = (16 + lo)*64 + ((g ^ sBr))*16;
  int rdB2 = (32 + lo)*64 + ((g ^ sBr))*16;
  int rdB3 = (48 + lo)*64 + ((g ^ sBr))*16;

  #define STAGE_A(n0v) do { \
    const char* gA = XLt + (size_t)(n0v)*128; \
    const char* gL = XLc + (size_t)(n0v)*2; \
    const char* gR = XRc + (size_t)(n0v)*2; \
    gload16(gA + aSrc[0], myA  + 0);    gload16(gA + aSrc[1], myA  + 1024); \
    gload16(gA + aSrc[2], myA  + 2048); gload16(gA + aSrc[3], myA  + 3072); \
    gload16(gL + bSrc[0], myBL + 0);    gload16(gL + bSrc[1], myBL + 1024); \
    gload16(gL + bSrc[2], myBL + 2048); gload16(gL + bSrc[3], myBL + 3072); \
    gload16(gR + bSrc[0], myBR + 0);    gload16(gR + bSrc[1], myBR + 1024); \
    gload16(gR + bSrc[2], myBR + 2048); gload16(gR + bSrc[3], myBR + 3072); \
  } while(0)

  f32x4 acc1A[4], acc2A[4], acc1B[4], acc2B[4];
  #pragma unroll
  for (int ct=0;ct<4;ct++){
    f32x4 z4 = {0.f,0.f,0.f,0.f};
    acc1A[ct]=z4; acc2A[ct]=z4; acc1B[ct]=z4; acc2B[ct]=z4;
  }
  float s1A = 0.f, s1B = 0.f;

  int nbeg = wv * 576;
  STAGE_A(nbeg);
  for (int s = 0; s < 18; ++s){
    int n0 = nbeg + s*32;
    asm volatile("s_waitcnt vmcnt(0)" ::: "memory");
    __builtin_amdgcn_sched_barrier(0);
    bf16x8 fa00 = *(const bf16x8*)(myA + rdA00);
    bf16x8 fa01 = *(const bf16x8*)(myA + rdA01);
    bf16x8 fa10 = *(const bf16x8*)(myA + rdA10);
    bf16x8 fa11 = *(const bf16x8*)(myA + rdA11);
    bf16x8 bL0 = *(const bf16x8*)(myBL + rdB0);
    bf16x8 bL1 = *(const bf16x8*)(myBL + rdB1);
    bf16x8 bL2 = *(const bf16x8*)(myBL + rdB2);
    bf16x8 bL3 = *(const bf16x8*)(myBL + rdB3);
    bf16x8 bR0 = *(const bf16x8*)(myBR + rdB0);
    bf16x8 bR1 = *(const bf16x8*)(myBR + rdB1);
    bf16x8 bR2 = *(const bf16x8*)(myBR + rdB2);
    bf16x8 bR3 = *(const bf16x8*)(myBR + rdB3);
    f32x4 r20 = *(const f32x4*)&rs2[n0 + 8*g];
    f32x4 r21 = *(const f32x4*)&rs2[n0 + 8*g + 4];
    asm volatile("s_waitcnt lgkmcnt(0)" ::: "memory");
    __builtin_amdgcn_sched_barrier(0);
    int n1 = (s+1 < 18) ? n0 + 32 : nbeg;
    STAGE_A(n1);
    __builtin_amdgcn_sched_barrier(0);

    f32x4 z4 = {0.f,0.f,0.f,0.f};
    f32x4 d0A = __builtin_amdgcn_mfma_f32_16x16x32_bf16(fa00, fmA0, z4, 0,0,0);
    d0A = __builtin_amdgcn_mfma_f32_16x16x32_bf16(fa01, fmA1, d0A, 0,0,0);
    f32x4 d1A = __builtin_amdgcn_mfma_f32_16x16x32_bf16(fa10, fmA0, z4, 0,0,0);
    d1A = __builtin_amdgcn_mfma_f32_16x16x32_bf16(fa11, fmA1, d1A, 0,0,0);
    f32x4 d0B = __builtin_amdgcn_mfma_f32_16x16x32_bf16(fa00, fmB0, z4, 0,0,0);
    d0B = __builtin_amdgcn_mfma_f32_16x16x32_bf16(fa01, fmB1, d0B, 0,0,0);
    f32x4 d1B = __builtin_amdgcn_mfma_f32_16x16x32_bf16(fa10, fmB0, z4, 0,0,0);
    d1B = __builtin_amdgcn_mfma_f32_16x16x32_bf16(fa11, fmB1, d1B, 0,0,0);

    bf16x8 pa1A, pa2A, pa1B, pa2B;
    #pragma unroll
    for (int r=0;r<4;r++){
      float e0 = exp2f(d0A[r]*L2E);
      float e1 = exp2f(d1A[r]*L2E);
      s1A += e0 + e1;
      pa1A[r]   = (bf16_t)e0;
      pa1A[r+4] = (bf16_t)e1;
      pa2A[r]   = (bf16_t)(e0 * r20[r]);
      pa2A[r+4] = (bf16_t)(e1 * r21[r]);
      float f0 = exp2f(d0B[r]*L2E);
      float f1 = exp2f(d1B[r]*L2E);
      s1B += f0 + f1;
      pa1B[r]   = (bf16_t)f0;
      pa1B[r+4] = (bf16_t)f1;
      pa2B[r]   = (bf16_t)(f0 * r20[r]);
      pa2B[r+4] = (bf16_t)(f1 * r21[r]);
    }
    acc1A[0] = __builtin_amdgcn_mfma_f32_16x16x32_bf16(pa1A, bL0, acc1A[0], 0,0,0);
    acc1A[1] = __builtin_amdgcn_mfma_f32_16x16x32_bf16(pa1A, bL1, acc1A[1], 0,0,0);
    acc1A[2] = __builtin_amdgcn_mfma_f32_16x16x32_bf16(pa1A, bL2, acc1A[2], 0,0,0);
    acc1A[3] = __builtin_amdgcn_mfma_f32_16x16x32_bf16(pa1A, bL3, acc1A[3], 0,0,0);
    acc2A[0] = __builtin_amdgcn_mfma_f32_16x16x32_bf16(pa2A, bR0, acc2A[0], 0,0,0);
    acc2A[1] = __builtin_amdgcn_mfma_f32_16x16x32_bf16(pa2A, bR1, acc2A[1], 0,0,0);
    acc2A[2] = __builtin_amdgcn_mfma_f32_16x16x32_bf16(pa2A, bR2, acc2A[2], 0,0,0);
    acc2A[3] = __builtin_amdgcn_mfma_f32_16x16x32_bf16(pa2A, bR3, acc2A[3], 0,0,0);
    acc1B[0] = __builtin_amdgcn_mfma_f32_16x16x32_bf16(pa1B, bL0, acc1B[0], 0,0,0);
    acc1B[1] = __builtin_amdgcn_mfma_f32_16x16x32_bf16(pa1B, bL1, acc1B[1], 0,0,0);
    acc1B[2] = __builtin_amdgcn_mfma_f32_16x16x32_bf16(pa1B, bL2, acc1B[2], 0,0,0);
    acc1B[3] = __builtin_amdgcn_mfma_f32_16x16x32_bf16(pa1B, bL3, acc1B[3], 0,0,0);
    acc2B[0] = __builtin_amdgcn_mfma_f32_16x16x32_bf16(pa2B, bR0, acc2B[0], 0,0,0);
    acc2B[1] = __builtin_amdgcn_mfma_f32_16x16x32_bf16(pa2B, bR1, acc2B[1], 0,0,0);
    acc2B[2] = __builtin_amdgcn_mfma_f32_16x16x32_bf16(pa2B, bR2, acc2B[2], 0,0,0);
    acc2B[3] = __builtin_amdgcn_mfma_f32_16x16x32_bf16(pa2B, bR3, acc2B[3], 0,0,0);
  }
  #undef STAGE_A

  asm volatile("s_waitcnt vmcnt(0)" ::: "memory");
  __syncthreads();

  // ---- LDS overlay (after staged loop) ----
  float (*bT1)[33]     = (float (*)[33])smraw;                     // 8448
  float (*bT2)[33]     = (float (*)[33])(smraw + 8448);            // 8448 -> 16896
  float (*red)[64][17] = (float (*)[64][17])(smraw + 16896);       // 17408 -> 34304
  u16   (*xT1)[34]     = (u16 (*)[34])(smraw + 34304);             // 4352 -> 38656
  u16   (*xT2)[34]     = (u16 (*)[34])(smraw + 38656);             // 4352 -> 43008
  float (*s1part)[32]  = (float (*)[32])(smraw + 43008);           // 512 -> 43520
  float* rs1inv        = (float*)(smraw + 43520);                  // 128 -> 43648
  float* gate          = (float*)(smraw + 43648);                  // 256 -> 43904

  int tt = threadIdx.x;

  // stage x tiles (channel-major, 32 m) while S1 reduces
  const u16* XLcu = (const u16*)XLc;
  const u16* XRcu = (const u16*)XRc;
  #pragma unroll
  for (int i=0;i<8;i++){
    int flat = i*256 + tt;
    int c = flat >> 5, mm = flat & 31;
    xT1[c][mm] = XLcu[(size_t)c*HW + m0 + mm];
    xT2[c][mm] = XRcu[(size_t)c*HW + m0 + mm];
  }

  // ---- S1 block reduction ----
  float s1Ar = s1A + __shfl_xor(s1A, 16, 64);
  s1Ar += __shfl_xor(s1Ar, 32, 64);
  float s1Br = s1B + __shfl_xor(s1B, 16, 64);
  s1Br += __shfl_xor(s1Br, 32, 64);
  if (lane < 16){ s1part[wv][lane] = s1Ar; s1part[wv][16+lane] = s1Br; }
  __syncthreads();
  if (tt < 32){
    float s = s1part[0][tt] + s1part[1][tt] + s1part[2][tt] + s1part[3][tt];
    rs1inv[tt] = 1.0f / s;
  }
  __syncthreads();

  // ---- 4 reduce phases -> LDS tiles (same sums/order as before) ----
  #define RED_TO(DSTARR, MBASE, SCALED) do { \
    _Pragma("unroll") \
    for (int pass=0; pass<4; ++pass){ \
      int c  = (tt>>4) + pass*16; \
      int mm = tt & 15; \
      int v  = ((c>>4)<<2) + (mm&3); \
      int ll = (c&15) + ((mm>>2)<<4); \
      float s = red[0][ll][v] + red[1][ll][v] + red[2][ll][v] + red[3][ll][v]; \
      DSTARR[c][(MBASE)+mm] = (SCALED) ? s * rs1inv[(MBASE)+mm] : s; \
    } \
  } while(0)

  #pragma unroll
  for (int v=0; v<16; ++v) red[wv][lane][v] = acc1A[v>>2][v&3];
  __syncthreads();
  RED_TO(bT1, 0, 1);
  __syncthreads();
  #pragma unroll
  for (int v=0; v<16; ++v) red[wv][lane][v] = acc2A[v>>2][v&3];
  __syncthreads();
  RED_TO(bT2, 0, 0);
  __syncthreads();
  #pragma unroll
  for (int v=0; v<16; ++v) red[wv][lane][v] = acc1B[v>>2][v&3];
  __syncthreads();
  RED_TO(bT1, 16, 1);
  __syncthreads();
  #pragma unroll
  for (int v=0; v<16; ++v) red[wv][lane][v] = acc2B[v>>2][v&3];
  __syncthreads();
  RED_TO(bT2, 16, 0);
  #undef RED_TO
  __syncthreads();

  // ---- gate: sigmoid(gw . b + gb) per position ----
  if (tt < 64){
    int mm = tt & 31;
    float a = 0.f;
    if (tt < 32){
      for (int c=0;c<64;c++) a = fmaf(gwL[c], bT1[c][mm], a);
      gate[tt] = 1.0f/(1.0f + exp2f(-(a + gbL[0])*L2E));
    } else {
      for (int c=0;c<64;c++) a = fmaf(gwR[c], bT2[c][mm], a);
      gate[tt] = 1.0f/(1.0f + exp2f(-(a + gbR[0])*L2E));
    }
  }
  __syncthreads();
  #pragma unroll
  for (int i=0;i<8;i++){
    int flat = i*256 + tt;
    int c = flat >> 5, mm = flat & 31;
    bT1[c][mm] *= gate[mm];
    bT2[c][mm] *= gate[32+mm];
  }
  __syncthreads();

  // ---- output conv: wave = (side, o-half); lane = (c-half, m) ----
  {
    int side = wv >> 1;                // waves 0,1 -> L; 2,3 -> R
    int ob   = (wv & 1) * 32;          // o base (32 outputs per wave)
    int mm   = lane & 31;
    int ch   = lane >> 5;              // c-half: 0 or 1
    const float* w    = side ? wRo : wLo;
    const float* bias = side ? bRo : bLo;
    float* outs = outp + ((size_t)side*B_ + b)*CH*HW;

    float xr[32], br[32];
    if (side == 0){
      #pragma unroll
      for (int cc=0;cc<32;cc++){ xr[cc] = bf2f(xT1[ch*32+cc][mm]); br[cc] = bT1[ch*32+cc][mm]; }
    } else {
      #pragma unroll
      for (int cc=0;cc<32;cc++){ xr[cc] = bf2f(xT2[ch*32+cc][mm]); br[cc] = bT2[ch*32+cc][mm]; }
    }
    for (int oi=0; oi<32; ++oi){
      int o = ob + oi;                 // wave-uniform
      const float* wr = &w[(size_t)o*128 + ch*32];
      float a = 0.f;
      #pragma unroll
      for (int cc=0;cc<32;cc++) a = fmaf(wr[cc],      xr[cc], a);
      #pragma unroll
      for (int cc=0;cc<32;cc++) a = fmaf(wr[64+cc],   br[cc], a);
      a += __shfl_xor(a, 32, 64);      // combine c-halves
      if (lane < 32) outs[(size_t)o*HW + m0 + mm] = a + bias[o];
    }
  }
}

extern "C" void kernel_launch(void* const* d_in, const int* in_sizes, int n_in,
                              void* d_out, int out_size, void* d_ws, size_t ws_size,
                              hipStream_t stream)
{
  char* ws = (char*)d_ws;
  k_proj <<<576, 256, 0, stream>>>(
      (const float*)d_in[0], (const float*)d_in[1],
      (const float*)d_in[2], (const float*)d_in[3],
      (const float*)d_in[4], (const float*)d_in[5],
      (const float*)d_in[6], (const float*)d_in[7], ws);
  k_stats<<<576, 256, 0, stream>>>(ws);
  k_attn <<<576, 256, 0, stream>>>(
      ws,
      (const float*)d_in[8],  (const float*)d_in[9],
      (const float*)d_in[10], (const float*)d_in[11],
      (const float*)d_in[12], (const float*)d_in[13],
      (const float*)d_in[14], (const float*)d_in[15],
      (float*)d_out);
}